// Round 17
// baseline (72.973 us; speedup 1.0000x reference)
//
#include <hip/hip_runtime.h>
#include <math.h>

#define NB   64
#define SEQ  1024
#define DIN  32
#define HID  256
#define QT   128
#define KT   64
#define NKT  (SEQ/KT)
#define LOG2E 1.4426950408889634f

typedef float        f32x16 __attribute__((ext_vector_type(16)));
typedef short        s16x8  __attribute__((ext_vector_type(8)));
typedef _Float16     f16x8  __attribute__((ext_vector_type(8)));
typedef unsigned int u32x4v __attribute__((ext_vector_type(4)));
typedef unsigned int u32x2v __attribute__((ext_vector_type(2)));

#define MFMA32(A,B,C)  __builtin_amdgcn_mfma_f32_32x32x16_bf16(A,B,C,0,0,0)
#define MFMA32H(A,B,C) __builtin_amdgcn_mfma_f32_32x32x16_f16(A,B,C,0,0,0)

// ---- ws byte offsets (fast path) ----
// ws[0..1055] f32: AT[32][32]*log2e + u[32]*log2e; OFF_WVT: u32[4096] WvT fp16.
#define OFF_WVT  4224
#define OFF_A    24576                      // [64*16][8192] A-frags hi|lo
#define OFF_T    (OFF_A + 64*16*8192)       // [64*16][4096] xkT-frags hi
#define WS_NEED  ((size_t)OFF_T + 64*16*4096)

// fallback LDS map
#define SETB(g,p) (((g)*2+(p))*12288)
#define ATS_OFF   49152
#define SMEM_SZ   (ATS_OFF + 4224)

__device__ __forceinline__ float ex2(float v) {      // 2^v, raw v_exp_f32
  return __builtin_amdgcn_exp2f(v);
}
__device__ __forceinline__ unsigned pk_bf16(float lo, float hi) {
  unsigned r;
  asm("v_cvt_pk_bf16_f32 %0, %1, %2" : "=v"(r) : "v"(lo), "v"(hi));
  return r;
}
__device__ __forceinline__ unsigned pkh(float a, float b) {
  return __builtin_bit_cast(unsigned, __builtin_amdgcn_cvt_pkrtz(a, b));
}
// new_dst = [dst.lo(lanes<32) | src.lo], new_src = [dst.hi | src.hi]
__device__ __forceinline__ void plswap(unsigned &vdst, unsigned &vsrc) {
  u32x2v r = __builtin_amdgcn_permlane32_swap(vdst, vsrc, false, false);
  vdst = r[0]; vsrc = r[1];
}
__device__ __forceinline__ float cross_max(float v) {
  u32x2v r = __builtin_amdgcn_permlane32_swap(__float_as_uint(v), __float_as_uint(v), false, false);
  return fmaxf(__uint_as_float(r[0]), __uint_as_float(r[1]));
}
__device__ __forceinline__ float cross_add(float v) {
  u32x2v r = __builtin_amdgcn_permlane32_swap(__float_as_uint(v), __float_as_uint(v), false, false);
  return __uint_as_float(r[0]) + __uint_as_float(r[1]);
}
__device__ __forceinline__ s16x8 frag4(unsigned a, unsigned b, unsigned c, unsigned d) {
  u32x4v t; t[0]=a; t[1]=b; t[2]=c; t[3]=d;
  return __builtin_bit_cast(s16x8, t);
}
__device__ __forceinline__ f16x8 frag4h(unsigned a, unsigned b, unsigned c, unsigned d) {
  u32x4v t; t[0]=a; t[1]=b; t[2]=c; t[3]=d;
  return __builtin_bit_cast(f16x8, t);
}
__device__ __forceinline__ f16x8 ldh(const void* p) {
  return __builtin_bit_cast(f16x8, *(const u32x4v*)p);
}
__device__ __forceinline__ unsigned bf16_hi_bits(float f) {
  unsigned ux = __float_as_uint(f);
  return (ux + 0x7fffu + ((ux >> 16) & 1u)) >> 16;
}
__device__ __forceinline__ unsigned pack_h2(float a, float b) {
  _Float16 ha = (_Float16)a, hb = (_Float16)b;
  return (unsigned)__builtin_bit_cast(unsigned short, ha) |
         ((unsigned)__builtin_bit_cast(unsigned short, hb) << 16);
}

// ====================== FAST PATH ======================

// Pack kernel, 1048 blocks (round-15 natural mapping — the round-16 XCD
// remap DOUBLED attn's HBM re-fetch; dispatch->XCD mapping is undefined,
// don't build on it):
//  [0,1024): one (b,kt) tile — coalesced x load -> padded LDS -> A/T frags.
//  [1024,1048): AT*log2e + u*log2e (ONCE) and WvT fp16 pairs.
__global__ __launch_bounds__(256) void pack2_kernel(
    const float* __restrict__ x,
    const float* __restrict__ Wq, const float* __restrict__ Wk,
    const float* __restrict__ bq, const float* __restrict__ Wv,
    char* __restrict__ ws) {
  __shared__ float xs[64 * 33];   // stride 33: kills column-read bank conflicts
  const int bid = blockIdx.x;
  const int t   = threadIdx.x;
  if (bid < 1024) {
    const int b = bid >> 4, kt = bid & 15;
    {
      const int r = t >> 2, c = (t & 3) * 8;
      const float* src = x + ((size_t)(b*SEQ + kt*KT + r))*DIN + c;
      float4 v0 = *(const float4*)src, v1 = *(const float4*)(src + 4);
      float* d = xs + r*33 + c;
      d[0]=v0.x; d[1]=v0.y; d[2]=v0.z; d[3]=v0.w;
      d[4]=v1.x; d[5]=v1.y; d[6]=v1.z; d[7]=v1.w;
    }
    __syncthreads();
    const int l = t & 63, f = t >> 6;
    const int w = l >> 5, lq = l & 31;
    // ---- A fragment (hi/lo fp16) ----
    {
      const int row = ((f&2)?32:0) + lq;
      const int d0  = ((f&1)?16:0) + 8*w;
      const float* vsrc = xs + row*33 + d0;
      unsigned hi[4], lo[4];
      #pragma unroll
      for (int j = 0; j < 4; ++j) {
        float a = vsrc[2*j], c2 = vsrc[2*j+1];
        _Float16 ha = (_Float16)a, hb = (_Float16)c2;
        hi[j] = (unsigned)__builtin_bit_cast(unsigned short, ha) |
                ((unsigned)__builtin_bit_cast(unsigned short, hb) << 16);
        lo[j] = pack_h2(a - (float)ha, c2 - (float)hb);
      }
      char* dst = ws + OFF_A + (size_t)bid*8192 + f*1024 + l*16;
      *(u32x4v*)dst          = (u32x4v){hi[0],hi[1],hi[2],hi[3]};
      *(u32x4v*)(dst + 4096) = (u32x4v){lo[0],lo[1],lo[2],lo[3]};
    }
    // ---- T fragment (hi fp16) ----
    {
      const int k0 = 16*f + 8*w;
      unsigned hi[4];
      #pragma unroll
      for (int j = 0; j < 4; ++j)
        hi[j] = pack_h2(xs[(k0 + 2*j)*33 + lq], xs[(k0 + 2*j + 1)*33 + lq]);
      char* dst = ws + OFF_T + (size_t)bid*4096 + f*1024 + l*16;
      *(u32x4v*)dst = (u32x4v){hi[0],hi[1],hi[2],hi[3]};
    }
  } else {
    const int gid = (bid - 1024) * 256 + t;
    float* wsf = (float*)ws;
    if (gid < 1024) {
      int i = gid >> 5, j = gid & 31;
      const float* a  = Wq + j * HID;
      const float* b2 = Wk + i * HID;
      float a0=0.f,a1=0.f,a2=0.f,a3=0.f;
      for (int h = 0; h < HID; h += 8) {
        float4 x1 = *(const float4*)(a + h),  y1 = *(const float4*)(b2 + h);
        float4 x2 = *(const float4*)(a + h+4), y2 = *(const float4*)(b2 + h+4);
        a0 = fmaf(x1.x,y1.x,a0); a1 = fmaf(x1.y,y1.y,a1);
        a2 = fmaf(x1.z,y1.z,a2); a3 = fmaf(x1.w,y1.w,a3);
        a0 = fmaf(x2.x,y2.x,a0); a1 = fmaf(x2.y,y2.y,a1);
        a2 = fmaf(x2.z,y2.z,a2); a3 = fmaf(x2.w,y2.w,a3);
      }
      wsf[gid] = ((a0+a1)+(a2+a3)) * LOG2E;   // exp2 domain
    } else if (gid < 1056) {
      int i2 = gid - 1024;
      const float* b2 = Wk + i2 * HID;
      float acc = 0.f;
      for (int h = 0; h < HID; ++h) acc = fmaf(b2[h], bq[h], acc);
      wsf[1024 + i2] = acc * LOG2E;           // exp2 domain
    } else if (gid < 1056 + HID*16) {
      int e = gid - 1056;
      int h = e >> 4, d = e & 15;
      ((unsigned*)(ws + OFF_WVT))[e] = pkh(Wv[(2*d)*HID + h], Wv[(2*d+1)*HID + h]);
    }
  }
}

// 2048 blocks x 256 threads = 4 waves = 4 k-groups over ONE 32-q subtile.
// Cooperative G'; exp2-domain softmax; main loop with REGISTER DOUBLE-BUFFERED
// A-frags (next iter's A loads issued before current compute — removes the
// GEMM1 head stall measured in r15/r16); T-frags at top of body (r15 position,
// hidden under GEMM1+softmax). 4-way merge. launch_bounds cap 128 VGPR.
__global__ __launch_bounds__(256, 4) void attn_fast(
    const float* __restrict__ x, const char* __restrict__ ws,
    const float* __restrict__ bv, float* __restrict__ out) {
  __shared__ __align__(16) char smem[20480];
  const int bid = blockIdx.x;
  const int vid = (bid & 7) * 256 + (bid >> 3);   // 2048 = 8 XCD * 256
  const int b   = vid >> 5;
  const int q0  = (vid & 31) * 32;
  const int t = threadIdx.x;
  const int wid = t>>6, lane = t&63, w = lane>>5, lq = lane&31;
  const int grp = wid;

  // ---- prologue: AT(+u) -> LDS (pad 33); cooperative G' -> LDS ----
  float* ATs = (float*)smem;               // [32][33] + u @1056..1087
  float* Gs  = (float*)(smem + 4480);      // [32][33]
  {
    const float* wsf = (const float*)ws;
    for (int e = t; e < 1024; e += 256) ATs[(e>>5)*33 + (e&31)] = wsf[e];
    if (t < 32) ATs[1056 + t] = wsf[1024 + t];
  }
  __syncthreads();
  {
    const int q = t >> 3, i0 = (t & 7) * 4;
    float xq[32];
    const float* xrow = x + (size_t)(b*SEQ + q0 + q) * DIN;
    #pragma unroll
    for (int c = 0; c < 8; ++c) {
      float4 v = *(const float4*)(xrow + c*4);
      xq[c*4+0]=v.x; xq[c*4+1]=v.y; xq[c*4+2]=v.z; xq[c*4+3]=v.w;
    }
    #pragma unroll
    for (int jo = 0; jo < 4; ++jo) {
      const int i = i0 + jo;
      const float* ar = ATs + i*33;
      float acc = ATs[1056 + i];
      #pragma unroll
      for (int j = 0; j < 32; ++j) acc = fmaf(xq[j], ar[j], acc);
      Gs[q*33 + i] = acc;
    }
  }
  __syncthreads();
  f16x8 G0h, G0l, G1h, G1l;
  {
    float g[16];
    #pragma unroll
    for (int ii = 0; ii < 16; ++ii) {
      const int i = 8*w + 16*(ii>>3) + (ii&7);
      g[ii] = Gs[lq*33 + i];
    }
    unsigned gh[8], gl[8];
    #pragma unroll
    for (int p = 0; p < 8; ++p) {
      float a = g[2*p], bb = g[2*p+1];
      _Float16 ha = (_Float16)a, hb = (_Float16)bb;
      gh[p] = (unsigned)__builtin_bit_cast(unsigned short, ha) |
              ((unsigned)__builtin_bit_cast(unsigned short, hb) << 16);
      gl[p] = pack_h2(a - (float)ha, bb - (float)hb);
    }
    G0h = frag4h(gh[0],gh[1],gh[2],gh[3]);
    G1h = frag4h(gh[4],gh[5],gh[6],gh[7]);
    G0l = frag4h(gl[0],gl[1],gl[2],gl[3]);
    G1l = frag4h(gl[4],gl[5],gl[6],gl[7]);
  }
  __syncthreads();   // LDS reused by merge

  f32x16 oacc;
  #pragma unroll
  for (int r = 0; r < 16; ++r) oacc[r] = 0.f;
  float m = -INFINITY, l = 0.f;

  const char* Ab = ws + OFF_A + (size_t)(b*16 + grp*4)*8192;
  const char* Tb = ws + OFF_T + (size_t)(b*16 + grp*4)*4096;
  const int lo16 = lane*16;

  // prefetch iter-0 A-frags
  f16x8 ah0 = ldh(Ab + 0*1024 + lo16);
  f16x8 ah1 = ldh(Ab + 1*1024 + lo16);
  f16x8 ah2 = ldh(Ab + 2*1024 + lo16);
  f16x8 ah3 = ldh(Ab + 3*1024 + lo16);
  f16x8 al0 = ldh(Ab + 4096 + 0*1024 + lo16);
  f16x8 al1 = ldh(Ab + 4096 + 1*1024 + lo16);
  f16x8 al2 = ldh(Ab + 4096 + 2*1024 + lo16);
  f16x8 al3 = ldh(Ab + 4096 + 3*1024 + lo16);

  #pragma unroll
  for (int j = 0; j < 4; ++j) {
    // T-frags for current iter (hidden under GEMM1 + softmax below)
    const char* T = Tb + j*4096;
    f16x8 at0 = ldh(T + 0*1024 + lo16);
    f16x8 at1 = ldh(T + 1*1024 + lo16);
    f16x8 at2 = ldh(T + 2*1024 + lo16);
    f16x8 at3 = ldh(T + 3*1024 + lo16);
    // prefetch next iter's A-frags (hidden under this iter's full body)
    f16x8 nah0, nah1, nah2, nah3, nal0, nal1, nal2, nal3;
    if (j < 3) {
      const char* An = Ab + (j+1)*8192;
      nah0 = ldh(An + 0*1024 + lo16);
      nah1 = ldh(An + 1*1024 + lo16);
      nah2 = ldh(An + 2*1024 + lo16);
      nah3 = ldh(An + 3*1024 + lo16);
      nal0 = ldh(An + 4096 + 0*1024 + lo16);
      nal1 = ldh(An + 4096 + 1*1024 + lo16);
      nal2 = ldh(An + 4096 + 2*1024 + lo16);
      nal3 = ldh(An + 4096 + 3*1024 + lo16);
    }

    // ---- GEMM1: S^T[64k x 32q], 3-term fp16 split (exp2 domain) ----
    f32x16 sa0, sa1;
    #pragma unroll
    for (int r = 0; r < 16; ++r) { sa0[r] = 0.f; sa1[r] = 0.f; }
    sa0 = MFMA32H(ah0, G0h, sa0); sa0 = MFMA32H(ah0, G0l, sa0); sa0 = MFMA32H(al0, G0h, sa0);
    sa0 = MFMA32H(ah1, G1h, sa0); sa0 = MFMA32H(ah1, G1l, sa0); sa0 = MFMA32H(al1, G1h, sa0);
    sa1 = MFMA32H(ah2, G0h, sa1); sa1 = MFMA32H(ah2, G0l, sa1); sa1 = MFMA32H(al2, G0h, sa1);
    sa1 = MFMA32H(ah3, G1h, sa1); sa1 = MFMA32H(ah3, G1l, sa1); sa1 = MFMA32H(al3, G1h, sa1);

    // ---- online softmax: tree max, defer-max (8*log2e), tree sum ----
    float t0 = fmaxf(fmaxf(sa0[0], sa0[1]),  fmaxf(sa0[2],  sa0[3]));
    float t1 = fmaxf(fmaxf(sa0[4], sa0[5]),  fmaxf(sa0[6],  sa0[7]));
    float t2 = fmaxf(fmaxf(sa0[8], sa0[9]),  fmaxf(sa0[10], sa0[11]));
    float t3 = fmaxf(fmaxf(sa0[12],sa0[13]), fmaxf(sa0[14], sa0[15]));
    float t4 = fmaxf(fmaxf(sa1[0], sa1[1]),  fmaxf(sa1[2],  sa1[3]));
    float t5 = fmaxf(fmaxf(sa1[4], sa1[5]),  fmaxf(sa1[6],  sa1[7]));
    float t6 = fmaxf(fmaxf(sa1[8], sa1[9]),  fmaxf(sa1[10], sa1[11]));
    float t7 = fmaxf(fmaxf(sa1[12],sa1[13]), fmaxf(sa1[14], sa1[15]));
    float tm = fmaxf(fmaxf(fmaxf(t0,t1), fmaxf(t2,t3)),
                     fmaxf(fmaxf(t4,t5), fmaxf(t6,t7)));
    tm = cross_max(tm);
    if (!__all(tm - m <= 11.5415603f)) {    // = 8 * log2(e)
      float mn = fmaxf(m, tm);
      float alpha = ex2(m - mn);
      m = mn;
      l *= alpha;
      #pragma unroll
      for (int r = 0; r < 16; ++r) oacc[r] *= alpha;
    }
    #pragma unroll
    for (int r = 0; r < 16; ++r) { sa0[r] = ex2(sa0[r] - m); sa1[r] = ex2(sa1[r] - m); }
    float s0 = (sa0[0] + sa0[1])  + (sa0[2]  + sa0[3]);
    float s1 = (sa0[4] + sa0[5])  + (sa0[6]  + sa0[7]);
    float s2 = (sa0[8] + sa0[9])  + (sa0[10] + sa0[11]);
    float s3 = (sa0[12]+ sa0[13]) + (sa0[14] + sa0[15]);
    float s4 = (sa1[0] + sa1[1])  + (sa1[2]  + sa1[3]);
    float s5 = (sa1[4] + sa1[5])  + (sa1[6]  + sa1[7]);
    float s6 = (sa1[8] + sa1[9])  + (sa1[10] + sa1[11]);
    float s7 = (sa1[12]+ sa1[13]) + (sa1[14] + sa1[15]);
    float ps = ((s0+s1) + (s2+s3)) + ((s4+s5) + (s6+s7));
    ps = cross_add(ps);
    l += ps;

    // ---- GEMM2: O^T += xkT * P (dst=low-pair) ----
    {
      unsigned u0 = pkh(sa0[0], sa0[1]),  u1 = pkh(sa0[2], sa0[3]);
      unsigned v0 = pkh(sa0[4], sa0[5]),  v1 = pkh(sa0[6], sa0[7]);
      plswap(u0, v0); plswap(u1, v1);
      oacc = MFMA32H(at0, frag4h(u0, u1, v0, v1), oacc);

      unsigned u2 = pkh(sa0[8], sa0[9]),   u3 = pkh(sa0[10], sa0[11]);
      unsigned v2 = pkh(sa0[12], sa0[13]), v3 = pkh(sa0[14], sa0[15]);
      plswap(u2, v2); plswap(u3, v3);
      oacc = MFMA32H(at1, frag4h(u2, u3, v2, v3), oacc);

      unsigned u4 = pkh(sa1[0], sa1[1]),  u5 = pkh(sa1[2], sa1[3]);
      unsigned v4 = pkh(sa1[4], sa1[5]),  v5 = pkh(sa1[6], sa1[7]);
      plswap(u4, v4); plswap(u5, v5);
      oacc = MFMA32H(at2, frag4h(u4, u5, v4, v5), oacc);

      unsigned u6 = pkh(sa1[8], sa1[9]),   u7 = pkh(sa1[10], sa1[11]);
      unsigned v6 = pkh(sa1[12], sa1[13]), v7 = pkh(sa1[14], sa1[15]);
      plswap(u6, v6); plswap(u7, v7);
      oacc = MFMA32H(at3, frag4h(u6, u7, v6, v7), oacc);
    }

    if (j < 3) {
      ah0 = nah0; ah1 = nah1; ah2 = nah2; ah3 = nah3;
      al0 = nal0; al1 = nal1; al2 = nal2; al3 = nal3;
    }
  }

  // ---- 4-way flash-merge across waves (symmetric, exp2 domain) ----
  {
    float* ms = (float*)(smem + ((wid<<6) | lane) * 80);
    *(float4*)(ms + 0)  = (float4){oacc[0],  oacc[1],  oacc[2],  oacc[3]};
    *(float4*)(ms + 4)  = (float4){oacc[4],  oacc[5],  oacc[6],  oacc[7]};
    *(float4*)(ms + 8)  = (float4){oacc[8],  oacc[9],  oacc[10], oacc[11]};
    *(float4*)(ms + 12) = (float4){oacc[12], oacc[13], oacc[14], oacc[15]};
    ms[16] = m; ms[17] = l;
    __syncthreads();
    #pragma unroll
    for (int og = 0; og < 4; ++og) {
      if (og == wid) continue;
      const float* pp = (const float*)(smem + ((og<<6) | lane) * 80);
      float4 p0 = *(const float4*)(pp + 0);
      float4 p1 = *(const float4*)(pp + 4);
      float4 p2 = *(const float4*)(pp + 8);
      float4 p3 = *(const float4*)(pp + 12);
      float pm = pp[16], pl = pp[17];
      float mf = fmaxf(m, pm);
      float as = ex2(m - mf), ap = ex2(pm - mf);
      l = l * as + pl * ap;
      float po[16] = {p0.x,p0.y,p0.z,p0.w, p1.x,p1.y,p1.z,p1.w,
                      p2.x,p2.y,p2.z,p2.w, p3.x,p3.y,p3.z,p3.w};
      #pragma unroll
      for (int r = 0; r < 16; ++r) oacc[r] = oacc[r] * as + po[r] * ap;
      m = mf;
    }
    __syncthreads();   // before zb reuse of this region
  }

  // ---- epilogue: Z^T = WvT * O_norm; wave handles mt = wid*2 + {0,1} ----
  float inv = 1.0f / (16.0f * l);
  #pragma unroll
  for (int r = 0; r < 16; ++r) oacc[r] *= inv;
  f16x8 of0, of1;
  {
    unsigned u0 = pkh(oacc[0], oacc[1]),  u1 = pkh(oacc[2], oacc[3]);
    unsigned v0 = pkh(oacc[4], oacc[5]),  v1 = pkh(oacc[6], oacc[7]);
    plswap(u0, v0); plswap(u1, v1);
    of0 = frag4h(u0, u1, v0, v1);
    unsigned u2 = pkh(oacc[8], oacc[9]),   u3 = pkh(oacc[10], oacc[11]);
    unsigned v2 = pkh(oacc[12], oacc[13]), v3 = pkh(oacc[14], oacc[15]);
    plswap(u2, v2); plswap(u3, v3);
    of1 = frag4h(u2, u3, v2, v3);
  }
  const char* WvTb = ws + OFF_WVT;
  float* zb = (float*)(smem + wid * 4224);
  const size_t orow = ((size_t)b * SEQ + q0);
  #pragma unroll 1
  for (int mi = 0; mi < 2; ++mi) {
    const int mt = wid*2 + mi;
    const char* wp = WvTb + (mt*32 + lq)*64 + 16*w;
    f16x8 a0 = ldh(wp);
    f16x8 a1 = ldh(wp + 32);
    f32x16 z;
    #pragma unroll
    for (int r = 0; r < 16; ++r) z[r] = 0.f;
    z = MFMA32H(a0, of0, z);
    z = MFMA32H(a1, of1, z);
    #pragma unroll
    for (int r = 0; r < 16; ++r) {
      int hl = (r&3) + 8*(r>>2) + 4*w;
      zb[hl*33 + lq] = z[r];
    }
    asm volatile("s_waitcnt lgkmcnt(0)" ::: "memory");
    float bvv = bv[mt*32 + lq] * 0.0625f;
    #pragma unroll
    for (int jj = 0; jj < 16; ++jj) {
      int q = w*16 + jj;
      out[(orow + q)*HID + mt*32 + lq] = zb[lq*33 + q] + bvv;
    }
    asm volatile("s_waitcnt lgkmcnt(0)" ::: "memory");
  }
}

// ====================== FALLBACK (round-6, proven) ======================

__global__ void precompute_kernel(const float* __restrict__ Wq, const float* __restrict__ Wk,
                                  const float* __restrict__ bq, const float* __restrict__ Wv,
                                  float* __restrict__ ws) {
  const int gid = blockIdx.x * 256 + threadIdx.x;
  if (gid < 1024) {
    int i = gid >> 5, j = gid & 31;
    const float* a  = Wq + j * HID;
    const float* b2 = Wk + i * HID;
    float a0=0.f,a1=0.f,a2=0.f,a3=0.f;
    for (int h = 0; h < HID; h += 8) {
      float4 x1 = *(const float4*)(a + h),  y1 = *(const float4*)(b2 + h);
      float4 x2 = *(const float4*)(a + h+4), y2 = *(const float4*)(b2 + h+4);
      a0 = fmaf(x1.x,y1.x,a0); a1 = fmaf(x1.y,y1.y,a1);
      a2 = fmaf(x1.z,y1.z,a2); a3 = fmaf(x1.w,y1.w,a3);
      a0 = fmaf(x2.x,y2.x,a0); a1 = fmaf(x2.y,y2.y,a1);
      a2 = fmaf(x2.z,y2.z,a2); a3 = fmaf(x2.w,y2.w,a3);
    }
    ws[gid] = (a0+a1)+(a2+a3);
  } else if (gid < 1056) {
    int i2 = gid - 1024;
    const float* b2 = Wk + i2 * HID;
    float acc = 0.f;
    for (int h = 0; h < HID; ++h) acc = fmaf(b2[h], bq[h], acc);
    ws[1024 + i2] = acc;
  } else if (gid < 1056 + HID*16) {
    int e = gid - 1056;
    int h = e >> 4, d = e & 15;
    ((unsigned*)((char*)ws + 4224))[e] = pk_bf16(Wv[(2*d)*HID + h], Wv[(2*d+1)*HID + h]);
  }
}

__global__ __launch_bounds__(512, 4) void attn_kernel(
    const float* __restrict__ x, const float* __restrict__ ws,
    const float* __restrict__ bv, float* __restrict__ out) {
  __shared__ __align__(16) char smem[SMEM_SZ];
  const int b    = blockIdx.y;
  const int q0   = blockIdx.x * QT;
  const int t    = threadIdx.x;
  const int grp  = t >> 8;
  const int ts   = t & 255;
  const int wid  = t >> 6;
  const int wq   = wid & 3;
  const int lane = t & 63;
  const int w    = lane >> 5;
  const int lq   = lane & 31;
  const float* xb = x + (size_t)b * SEQ * DIN;

  float* ATs = (float*)(smem + ATS_OFF);
  for (int e = t; e < 1056; e += 512) ATs[e] = ws[e];

  {
    const int sb = SETB(grp, 0);
    const int r = ts >> 2, s4 = ts & 3;
    const float* src = xb + (size_t)(grp * KT + r) * DIN + s4 * 8;
    float4 va = *(const float4*)src;
    float4 vb = *(const float4*)(src + 4);
    unsigned h0 = bf16_hi_bits(va.x) | (bf16_hi_bits(va.y) << 16);
    unsigned h1 = bf16_hi_bits(va.z) | (bf16_hi_bits(va.w) << 16);
    unsigned h2 = bf16_hi_bits(vb.x) | (bf16_hi_bits(vb.y) << 16);
    unsigned h3 = bf16_hi_bits(vb.z) | (bf16_hi_bits(vb.w) << 16);
    unsigned l0 = bf16_hi_bits(va.x - __uint_as_float(h0<<16)) | (bf16_hi_bits(va.y - __uint_as_float(h0 & 0xffff0000u)) << 16);
    unsigned l1 = bf16_hi_bits(va.z - __uint_as_float(h1<<16)) | (bf16_hi_bits(va.w - __uint_as_float(h1 & 0xffff0000u)) << 16);
    unsigned l2 = bf16_hi_bits(vb.x - __uint_as_float(h2<<16)) | (bf16_hi_bits(vb.y - __uint_as_float(h2 & 0xffff0000u)) << 16);
    unsigned l3 = bf16_hi_bits(vb.z - __uint_as_float(h3<<16)) | (bf16_hi_bits(vb.w - __uint_as_float(h3 & 0xffff0000u)) << 16);
    int off = r*64 + ((s4 ^ (r & 3)) << 4);
    *(u32x4v*)(smem + sb + off)        = (u32x4v){h0,h1,h2,h3};
    *(u32x4v*)(smem + sb + 4096 + off) = (u32x4v){l0,l1,l2,l3};
    const int ci = ts & 31, cr = (ts >> 5) * 8;
    const float* cs = xb + (size_t)(grp * KT + cr) * DIN + ci;
    float c0=cs[0], c1=cs[DIN], c2=cs[2*DIN], c3=cs[3*DIN];
    float c4=cs[4*DIN], c5=cs[5*DIN], c6=cs[6*DIN], c7=cs[7*DIN];
    unsigned t0 = pk_bf16(c0,c1), t1 = pk_bf16(c2,c3), t2 = pk_bf16(c4,c5), t3 = pk_bf16(c6,c7);
    int toff = sb + 8192 + ci*128 + (((ts>>5) ^ (ci & 7)) << 4);
    *(u32x4v*)(smem + toff) = (u32x4v){t0,t1,t2,t3};
  }
  __syncthreads();

  float g[16];
  {
    float xq[32];
    const float* xrow = xb + (size_t)(q0 + wq*32 + lq) * DIN;
    #pragma unroll
    for (int c = 0; c < 8; ++c) {
      float4 v = *(const float4*)(xrow + c*4);
      xq[c*4+0]=v.x; xq[c*4+1]=v.y; xq[c*4+2]=v.z; xq[c*4+3]=v.w;
    }
    #pragma unroll
    for (int ii = 0; ii < 16; ++ii) {
      const int i = 8*w + 16*(ii>>3) + (ii&7);
      const float* ar = ATs + i*32;
      float acc = ATs[1024 + i];
      #pragma unroll
      for (int j = 0; j < 8; ++j) {
        float4 av = *(const float4*)(ar + j*4);
        acc = fmaf(xq[j*4+0], av.x, acc);
        acc = fmaf(xq[j*4+1], av.y, acc);
        acc = fmaf(xq[j*4+2], av.z, acc);
        acc = fmaf(xq[j*4+3], av.w, acc);
      }
      g[ii] = acc;
    }
  }
  s16x8 G0h, G0l, G1h, G1l;
  {
    unsigned gh[2][4], gl[2][4];
    #pragma unroll
    for (int Ks = 0; Ks < 2; ++Ks)
      #pragma unroll
      for (int d = 0; d < 4; ++d) {
        float ga = g[Ks*8 + 2*d], gb = g[Ks*8 + 2*d + 1];
        unsigned hp = bf16_hi_bits(ga) | (bf16_hi_bits(gb) << 16);
        unsigned lp = bf16_hi_bits(ga - __uint_as_float(hp<<16)) |
                      (bf16_hi_bits(gb - __uint_as_float(hp & 0xffff0000u)) << 16);
        gh[Ks][d] = hp; gl[Ks][d] = lp;
      }
    G0h = frag4(gh[0][0],gh[0][1],gh[0][2],gh[0][3]);
    G0l = frag4(gl[0][0],gl[0][1],gl[0][2],gl[0][3]);
    G1h = frag4(gh[1][0],gh[1][1],gh[1][2],gh[1][3]);
    G1l = frag4(gl[1][0],gl[1][1],gl[1][2],gl[1][3]);
  }

  f32x16 oacc;
  #pragma unroll
  for (int r = 0; r < 16; ++r) oacc[r] = 0.f;
  float m = -INFINITY, l = 0.f;

  for (int j = 0; j < NKT/2; ++j) {
    const bool hn = (j + 1 < NKT/2);
    float4 va, vb;
    float c0=0,c1=0,c2=0,c3=0,c4=0,c5=0,c6=0,c7=0;
    if (hn) {
      const int ktn = 2*(j+1) + grp;
      const int r = ts >> 2, s4 = ts & 3;
      const float* src = xb + (size_t)(ktn*KT + r) * DIN + s4*8;
      va = *(const float4*)src;
      vb = *(const float4*)(src + 4);
      const int ci = ts & 31, cr = (ts >> 5) * 8;
      const float* cs = xb + (size_t)(ktn*KT + cr) * DIN + ci;
      c0=cs[0]; c1=cs[DIN]; c2=cs[2*DIN]; c3=cs[3*DIN];
      c4=cs[4*DIN]; c5=cs[5*DIN]; c6=cs[6*DIN]; c7=cs[7*DIN];
    }

    const int sb = SETB(grp, j & 1);
    const char* bh = smem + sb;
    const char* bl = smem + sb + 4096;
    const int co0 = ((w    ) ^ (lq & 3)) << 4;
    const int co1 = ((w + 2) ^ (lq & 3)) << 4;
    s16x8 ah00 = *(const s16x8*)(bh + lq*64 + co0);
    s16x8 ah01 = *(const s16x8*)(bh + lq*64 + co1);
    s16x8 al00 = *(const s16x8*)(bl + lq*64 + co0);
    s16x8 al01 = *(const s16x8*)(bl + lq*64 + co1);
    s16x8 ah10 = *(const s16x8*)(bh + (32+lq)*64 + co0);
    s16x8 ah11 = *(const s16x8*)(bh + (32+lq)*64 + co1);
    s16x8 al10 = *(const s16x8*)(bl + (32+lq)*64 + co0);
    s16x8 al11 = *(const s16x8*)(bl + (32+lq)*64 + co1);
    f32x16 sa0, sa1;
    #pragma unroll
    for (int r = 0; r < 16; ++r) { sa0[r] = 0.f; sa1[r] = 0.f; }
    sa0 = MFMA32(ah00, G0h, sa0); sa0 = MFMA32(ah00, G0l, sa0); sa0 = MFMA32(al00, G0h, sa0);
    sa0 = MFMA32(ah01, G1h, sa0); sa0 = MFMA32(ah01, G1l, sa0); sa0 = MFMA32(al01, G1h, sa0);
    sa1 = MFMA32(ah10, G0h, sa1); sa1 = MFMA32(ah10, G0l, sa1); sa1 = MFMA32(al10, G0h, sa1);
    sa1 = MFMA32(ah11, G1h, sa1); sa1 = MFMA32(ah11, G1l, sa1); sa1 = MFMA32(al11, G1h, sa1);

    float tm = sa0[0];
    #pragma unroll
    for (int r = 1; r < 16; ++r) tm = fmaxf(tm, sa0[r]);
    #pragma unroll
    for (int r = 0; r < 16; ++r) tm = fmaxf(tm, sa1[r]);
    tm = cross_max(tm);
    float mn = fmaxf(m, tm);
    float alpha = __expf(m - mn);
    m = mn;
    float ps = 0.f;
    #pragma unroll
    for (int r = 0; r < 16; ++r) { float p = __expf(sa0[r] - mn); sa0[r] = p; ps += p; }
    #pragma unroll
    for (int r = 0; r < 16; ++r) { float p = __expf(sa1[r] - mn); sa1[r] = p; ps += p; }
    ps = cross_add(ps);
    l = l * alpha + ps;
    #pragma unroll
    for (int r = 0; r < 16; ++r) oacc[r] *= alpha;

    const char* bt = smem + sb + 8192;
    {
      unsigned u0 = pk_bf16(sa0[0], sa0[1]),  u1 = pk_bf16(sa0[2], sa0[3]);
      unsigned v0 = pk_bf16(sa0[4], sa0[5]),  v1 = pk_bf16(sa0[6], sa0[7]);
      plswap(u0, v0); plswap(u1, v1);
      s16x8 at0 = *(const s16x8*)(bt + lq*128 + (((0 + w) ^ (lq & 7)) << 4));
      oacc = MFMA32(at0, frag4(u0, u1, v0, v1), oacc);

      unsigned u2 = pk_bf16(sa0[8], sa0[9]),   u3 = pk_bf16(sa0[10], sa0[11]);
      unsigned v2 = pk_bf16(sa0[12], sa0[13]), v3 = pk_bf16(sa0[14], sa0[15]);
      plswap(u2, v2); plswap(u3, v3);
      s16x8 at1 = *(const s16x8*)(bt + lq*128 + (((2 + w) ^ (lq & 7)) << 4));
      oacc = MFMA32(at1, frag4(u2, u3, v2, v3), oacc);

      unsigned u4 = pk_bf16(sa1[0], sa1[1]),  u5 = pk_bf16(sa1[2], sa1[3]);
      unsigned v4 = pk_bf16(sa1[4], sa1[5]),  v5 = pk_bf16(sa1[6], sa1[7]);
      plswap(u4, v4); plswap(u5, v5);
      s16x8 at2 = *(const s16x8*)(bt + lq*128 + (((4 + w) ^ (lq & 7)) << 4));
      oacc = MFMA32(at2, frag4(u4, u5, v4, v5), oacc);

      unsigned u6 = pk_bf16(sa1[8], sa1[9]),   u7 = pk_bf16(sa1[10], sa1[11]);
      unsigned v6 = pk_bf16(sa1[12], sa1[13]), v7 = pk_bf16(sa1[14], sa1[15]);
      plswap(u6, v6); plswap(u7, v7);
      s16x8 at3 = *(const s16x8*)(bt + lq*128 + (((6 + w) ^ (lq & 7)) << 4));
      oacc = MFMA32(at3, frag4(u6, u7, v6, v7), oacc);
    }

    if (hn) {
      const int nsb = SETB(grp, (j+1) & 1);
      const int r = ts >> 2, s4 = ts & 3;
      unsigned h0 = bf16_hi_bits(va.x) | (bf16_hi_bits(va.y) << 16);
      unsigned h1 = bf16_hi_bits(va.z) | (bf16_hi_bits(va.w) << 16);
      unsigned h2 = bf16_hi_bits(vb.x) | (bf16_hi_bits(vb.y) << 16);
      unsigned h3 = bf16_hi_bits(vb.z) | (bf16_hi_bits(vb.w) << 16);
      unsigned l0 = bf16_hi_bits(va.x - __uint_as_float(h0<<16)) | (bf16_hi_bits(va.y - __uint_as_float(h0 & 0xffff0000u)) << 16);
      unsigned l1 = bf16_hi_bits(va.z - __uint_as_float(h1<<16)) | (bf16_hi_bits(va.w - __uint_as_float(h1 & 0xffff0000u)) << 16);
      unsigned l2 = bf16_hi_bits(vb.x - __uint_as_float(h2<<16)) | (bf16_hi_bits(vb.y - __uint_as_float(h2 & 0xffff0000u)) << 16);
      unsigned l3 = bf16_hi_bits(vb.z - __uint_as_float(h3<<16)) | (bf16_hi_bits(vb.w - __uint_as_float(h3 & 0xffff0000u)) << 16);
      int off = r*64 + ((s4 ^ (r & 3)) << 4);
      *(u32x4v*)(smem + nsb + off)        = (u32x4v){h0,h1,h2,h3};
      *(u32x4v*)(smem + nsb + 4096 + off) = (u32x4v){l0,l1,l2,l3};
      const int ci = ts & 31;
      unsigned t0 = pk_bf16(c0,c1), t1 = pk_bf16(c2,c3), t2 = pk_bf16(c4,c5), t3 = pk_bf16(c6,c7);
      int toff = nsb + 8192 + ci*128 + (((ts>>5) ^ (ci & 7)) << 4);
      *(u32x4v*)(smem + toff) = (u32x4v){t0,t1,t2,t3};
    }
    __syncthreads();
  }

  {
    float* ms = (float*)(smem + grp*20480 + (((wq<<6) | lane) * 80));
    *(float4*)(ms + 0)  = (float4){oacc[0],  oacc[1],  oacc[2],  oacc[3]};
    *(float4*)(ms + 4)  = (float4){oacc[4],  oacc[5],  oacc[6],  oacc[7]};
    *(float4*)(ms + 8)  = (float4){oacc[8],  oacc[9],  oacc[10], oacc[11]};
    *(float4*)(ms + 12) = (float4){oacc[12], oacc[13], oacc[14], oacc[15]};
    ms[16] = m; ms[17] = l;
    __syncthreads();
    const float* pp = (const float*)(smem + (1-grp)*20480 + (((wq<<6) | lane) * 80));
    float4 p0 = *(const float4*)(pp + 0);
    float4 p1 = *(const float4*)(pp + 4);
    float4 p2 = *(const float4*)(pp + 8);
    float4 p3 = *(const float4*)(pp + 12);
    float pm = pp[16], pl = pp[17];
    float mf = fmaxf(m, pm);
    float as = __expf(m - mf), ap = __expf(pm - mf);
    l = l * as + pl * ap;
    float po[16] = {p0.x,p0.y,p0.z,p0.w, p1.x,p1.y,p1.z,p1.w,
                    p2.x,p2.y,p2.z,p2.w, p3.x,p3.y,p3.z,p3.w};
    #pragma unroll
    for (int r = 0; r < 16; ++r) oacc[r] = oacc[r] * as + po[r] * ap;
    __syncthreads();
  }

  float inv = 1.0f / (16.0f * l);
  #pragma unroll
  for (int r = 0; r < 16; ++r) oacc[r] *= inv;
  s16x8 of0, of1;
  {
    unsigned u0 = pk_bf16(oacc[0], oacc[1]),  u1 = pk_bf16(oacc[2], oacc[3]);
    unsigned v0 = pk_bf16(oacc[4], oacc[5]),  v1 = pk_bf16(oacc[6], oacc[7]);
    plswap(u0, v0); plswap(u1, v1);
    of0 = frag4(u0, u1, v0, v1);
    unsigned u2 = pk_bf16(oacc[8], oacc[9]),   u3 = pk_bf16(oacc[10], oacc[11]);
    unsigned v2 = pk_bf16(oacc[12], oacc[13]), v3 = pk_bf16(oacc[14], oacc[15]);
    plswap(u2, v2); plswap(u3, v3);
    of1 = frag4(u2, u3, v2, v3);
  }
  const char* WvTb = (const char*)ws + 4224;
  float* zb = (float*)(smem + wid * 4224);
  const size_t orow = ((size_t)b * SEQ + q0 + wq*32);
  #pragma unroll 1
  for (int mi = 0; mi < 4; ++mi) {
    const int mt = grp*4 + mi;
    const char* wp = WvTb + (mt*32 + lq)*64 + 16*w;
    s16x8 a0 = *(const s16x8*)wp;
    s16x8 a1 = *(const s16x8*)(wp + 32);
    f32x16 z;
    #pragma unroll
    for (int r = 0; r < 16; ++r) z[r] = 0.f;
    z = MFMA32(a0, of0, z);
    z = MFMA32(a1, of1, z);
    #pragma unroll
    for (int r = 0; r < 16; ++r) {
      int hl = (r&3) + 8*(r>>2) + 4*w;
      zb[hl*33 + lq] = z[r];
    }
    asm volatile("s_waitcnt lgkmcnt(0)" ::: "memory");
    float bvv = bv[mt*32 + lq] * 0.0625f;
    #pragma unroll
    for (int jj = 0; jj < 16; ++jj) {
      int q = w*16 + jj;
      out[(orow + q)*HID + mt*32 + lq] = zb[lq*33 + q] + bvv;
    }
    asm volatile("s_waitcnt lgkmcnt(0)" ::: "memory");
  }
}

extern "C" void kernel_launch(void* const* d_in, const int* in_sizes, int n_in,
                              void* d_out, int out_size, void* d_ws, size_t ws_size,
                              hipStream_t stream) {
  (void)in_sizes; (void)n_in; (void)out_size;
  const float* x  = (const float*)d_in[0];
  const float* Wq = (const float*)d_in[1];
  const float* bq = (const float*)d_in[2];
  const float* Wk = (const float*)d_in[3];
  const float* Wv = (const float*)d_in[5];
  const float* bv = (const float*)d_in[6];
  float* out = (float*)d_out;
  float* ws  = (float*)d_ws;

  if (ws_size >= WS_NEED) {
    pack2_kernel<<<1048, 256, 0, stream>>>(x, Wq, Wk, bq, Wv, (char*)ws);
    attn_fast<<<2048, 256, 0, stream>>>(x, (const char*)ws, bv, out);
  } else {
    precompute_kernel<<<24, 256, 0, stream>>>(Wq, Wk, bq, Wv, ws);
    attn_kernel<<<dim3(SEQ/QT, NB), 512, 0, stream>>>(x, ws, bv, out);
  }
}

// Round 18
// 58.057 us; speedup vs baseline: 1.2569x; 1.2569x over previous
//
#include <hip/hip_runtime.h>
#include <math.h>

#define NB   64
#define SEQ  1024
#define DIN  32
#define HID  256
#define QT   128
#define KT   64
#define NKT  (SEQ/KT)
#define LOG2E 1.4426950408889634f

typedef float        f32x16 __attribute__((ext_vector_type(16)));
typedef short        s16x8  __attribute__((ext_vector_type(8)));
typedef _Float16     f16x8  __attribute__((ext_vector_type(8)));
typedef unsigned int u32x4v __attribute__((ext_vector_type(4)));
typedef unsigned int u32x2v __attribute__((ext_vector_type(2)));

#define MFMA32(A,B,C)  __builtin_amdgcn_mfma_f32_32x32x16_bf16(A,B,C,0,0,0)
#define MFMA32H(A,B,C) __builtin_amdgcn_mfma_f32_32x32x16_f16(A,B,C,0,0,0)

// ---- ws byte offsets (fast path) ----
// ws[0..1055] f32: AT[32][32]*log2e + u[32]*log2e; OFF_WVT: u32[4096] WvT fp16.
#define OFF_WVT  4224
#define OFF_A    24576                      // [64*16][8192] A-frags hi|lo
#define OFF_T    (OFF_A + 64*16*8192)       // [64*16][4096] xkT-frags hi
#define WS_NEED  ((size_t)OFF_T + 64*16*4096)

// fallback LDS map
#define SETB(g,p) (((g)*2+(p))*12288)
#define ATS_OFF   49152
#define SMEM_SZ   (ATS_OFF + 4224)

__device__ __forceinline__ float ex2(float v) {      // 2^v, raw v_exp_f32
  return __builtin_amdgcn_exp2f(v);
}
__device__ __forceinline__ unsigned pk_bf16(float lo, float hi) {
  unsigned r;
  asm("v_cvt_pk_bf16_f32 %0, %1, %2" : "=v"(r) : "v"(lo), "v"(hi));
  return r;
}
__device__ __forceinline__ unsigned pkh(float a, float b) {
  return __builtin_bit_cast(unsigned, __builtin_amdgcn_cvt_pkrtz(a, b));
}
// new_dst = [dst.lo(lanes<32) | src.lo], new_src = [dst.hi | src.hi]
__device__ __forceinline__ void plswap(unsigned &vdst, unsigned &vsrc) {
  u32x2v r = __builtin_amdgcn_permlane32_swap(vdst, vsrc, false, false);
  vdst = r[0]; vsrc = r[1];
}
__device__ __forceinline__ float cross_max(float v) {
  u32x2v r = __builtin_amdgcn_permlane32_swap(__float_as_uint(v), __float_as_uint(v), false, false);
  return fmaxf(__uint_as_float(r[0]), __uint_as_float(r[1]));
}
__device__ __forceinline__ float cross_add(float v) {
  u32x2v r = __builtin_amdgcn_permlane32_swap(__float_as_uint(v), __float_as_uint(v), false, false);
  return __uint_as_float(r[0]) + __uint_as_float(r[1]);
}
__device__ __forceinline__ s16x8 frag4(unsigned a, unsigned b, unsigned c, unsigned d) {
  u32x4v t; t[0]=a; t[1]=b; t[2]=c; t[3]=d;
  return __builtin_bit_cast(s16x8, t);
}
__device__ __forceinline__ f16x8 frag4h(unsigned a, unsigned b, unsigned c, unsigned d) {
  u32x4v t; t[0]=a; t[1]=b; t[2]=c; t[3]=d;
  return __builtin_bit_cast(f16x8, t);
}
__device__ __forceinline__ f16x8 ldh(const void* p) {
  return __builtin_bit_cast(f16x8, *(const u32x4v*)p);
}
__device__ __forceinline__ unsigned bf16_hi_bits(float f) {
  unsigned ux = __float_as_uint(f);
  return (ux + 0x7fffu + ((ux >> 16) & 1u)) >> 16;
}
__device__ __forceinline__ unsigned pack_h2(float a, float b) {
  _Float16 ha = (_Float16)a, hb = (_Float16)b;
  return (unsigned)__builtin_bit_cast(unsigned short, ha) |
         ((unsigned)__builtin_bit_cast(unsigned short, hb) << 16);
}

// ====================== FAST PATH (round-15 proven best: 58.2us) ======================

// Pack kernel, 1048 blocks:
//  [0,1024): one (b,kt) tile — coalesced x load -> padded LDS -> A/T frags.
//  [1024,1048): AT*log2e + u*log2e (ONCE) and WvT fp16 pairs.
__global__ __launch_bounds__(256) void pack2_kernel(
    const float* __restrict__ x,
    const float* __restrict__ Wq, const float* __restrict__ Wk,
    const float* __restrict__ bq, const float* __restrict__ Wv,
    char* __restrict__ ws) {
  __shared__ float xs[64 * 33];   // stride 33: kills column-read bank conflicts
  const int bid = blockIdx.x;
  const int t   = threadIdx.x;
  if (bid < 1024) {
    const int b = bid >> 4, kt = bid & 15;
    {
      const int r = t >> 2, c = (t & 3) * 8;
      const float* src = x + ((size_t)(b*SEQ + kt*KT + r))*DIN + c;
      float4 v0 = *(const float4*)src, v1 = *(const float4*)(src + 4);
      float* d = xs + r*33 + c;
      d[0]=v0.x; d[1]=v0.y; d[2]=v0.z; d[3]=v0.w;
      d[4]=v1.x; d[5]=v1.y; d[6]=v1.z; d[7]=v1.w;
    }
    __syncthreads();
    const int l = t & 63, f = t >> 6;
    const int w = l >> 5, lq = l & 31;
    // ---- A fragment (hi/lo fp16) ----
    {
      const int row = ((f&2)?32:0) + lq;
      const int d0  = ((f&1)?16:0) + 8*w;
      const float* vsrc = xs + row*33 + d0;
      unsigned hi[4], lo[4];
      #pragma unroll
      for (int j = 0; j < 4; ++j) {
        float a = vsrc[2*j], c2 = vsrc[2*j+1];
        _Float16 ha = (_Float16)a, hb = (_Float16)c2;
        hi[j] = (unsigned)__builtin_bit_cast(unsigned short, ha) |
                ((unsigned)__builtin_bit_cast(unsigned short, hb) << 16);
        lo[j] = pack_h2(a - (float)ha, c2 - (float)hb);
      }
      char* dst = ws + OFF_A + (size_t)bid*8192 + f*1024 + l*16;
      *(u32x4v*)dst          = (u32x4v){hi[0],hi[1],hi[2],hi[3]};
      *(u32x4v*)(dst + 4096) = (u32x4v){lo[0],lo[1],lo[2],lo[3]};
    }
    // ---- T fragment (hi fp16) ----
    {
      const int k0 = 16*f + 8*w;
      unsigned hi[4];
      #pragma unroll
      for (int j = 0; j < 4; ++j)
        hi[j] = pack_h2(xs[(k0 + 2*j)*33 + lq], xs[(k0 + 2*j + 1)*33 + lq]);
      char* dst = ws + OFF_T + (size_t)bid*4096 + f*1024 + l*16;
      *(u32x4v*)dst = (u32x4v){hi[0],hi[1],hi[2],hi[3]};
    }
  } else {
    const int gid = (bid - 1024) * 256 + t;
    float* wsf = (float*)ws;
    if (gid < 1024) {
      int i = gid >> 5, j = gid & 31;
      const float* a  = Wq + j * HID;
      const float* b2 = Wk + i * HID;
      float a0=0.f,a1=0.f,a2=0.f,a3=0.f;
      for (int h = 0; h < HID; h += 8) {
        float4 x1 = *(const float4*)(a + h),  y1 = *(const float4*)(b2 + h);
        float4 x2 = *(const float4*)(a + h+4), y2 = *(const float4*)(b2 + h+4);
        a0 = fmaf(x1.x,y1.x,a0); a1 = fmaf(x1.y,y1.y,a1);
        a2 = fmaf(x1.z,y1.z,a2); a3 = fmaf(x1.w,y1.w,a3);
        a0 = fmaf(x2.x,y2.x,a0); a1 = fmaf(x2.y,y2.y,a1);
        a2 = fmaf(x2.z,y2.z,a2); a3 = fmaf(x2.w,y2.w,a3);
      }
      wsf[gid] = ((a0+a1)+(a2+a3)) * LOG2E;   // exp2 domain
    } else if (gid < 1056) {
      int i2 = gid - 1024;
      const float* b2 = Wk + i2 * HID;
      float acc = 0.f;
      for (int h = 0; h < HID; ++h) acc = fmaf(b2[h], bq[h], acc);
      wsf[1024 + i2] = acc * LOG2E;           // exp2 domain
    } else if (gid < 1056 + HID*16) {
      int e = gid - 1056;
      int h = e >> 4, d = e & 15;
      ((unsigned*)(ws + OFF_WVT))[e] = pkh(Wv[(2*d)*HID + h], Wv[(2*d+1)*HID + h]);
    }
  }
}

// 2048 blocks x 256 threads = 4 waves = 4 k-groups over ONE 32-q subtile.
// Cooperative G'; exp2-domain softmax; barrier-free main loop (unroll 2,
// all frag loads at top of body); 4-way merge; epilogue 2 mt/wave.
// NOTE (r16/r17 lessons): XCD-remap of pack DOUBLED re-fetch (dispatch->XCD
// undefined); register double-buffer spilled at pinned VGPR=64 (80MB scratch).
// This r15 configuration is the measured optimum: 43.9us, FETCH 10.4MB.
__global__ __launch_bounds__(256, 4) void attn_fast(
    const float* __restrict__ x, const char* __restrict__ ws,
    const float* __restrict__ bv, float* __restrict__ out) {
  __shared__ __align__(16) char smem[20480];
  const int bid = blockIdx.x;
  const int vid = (bid & 7) * 256 + (bid >> 3);   // 2048 = 8 XCD * 256
  const int b   = vid >> 5;
  const int q0  = (vid & 31) * 32;
  const int t = threadIdx.x;
  const int wid = t>>6, lane = t&63, w = lane>>5, lq = lane&31;
  const int grp = wid;

  // ---- prologue: AT(+u) -> LDS (pad 33); cooperative G' -> LDS ----
  float* ATs = (float*)smem;               // [32][33] + u @1056..1087
  float* Gs  = (float*)(smem + 4480);      // [32][33]
  {
    const float* wsf = (const float*)ws;
    for (int e = t; e < 1024; e += 256) ATs[(e>>5)*33 + (e&31)] = wsf[e];
    if (t < 32) ATs[1056 + t] = wsf[1024 + t];
  }
  __syncthreads();
  {
    const int q = t >> 3, i0 = (t & 7) * 4;
    float xq[32];
    const float* xrow = x + (size_t)(b*SEQ + q0 + q) * DIN;
    #pragma unroll
    for (int c = 0; c < 8; ++c) {
      float4 v = *(const float4*)(xrow + c*4);
      xq[c*4+0]=v.x; xq[c*4+1]=v.y; xq[c*4+2]=v.z; xq[c*4+3]=v.w;
    }
    #pragma unroll
    for (int jo = 0; jo < 4; ++jo) {
      const int i = i0 + jo;
      const float* ar = ATs + i*33;
      float acc = ATs[1056 + i];
      #pragma unroll
      for (int j = 0; j < 32; ++j) acc = fmaf(xq[j], ar[j], acc);
      Gs[q*33 + i] = acc;
    }
  }
  __syncthreads();
  f16x8 G0h, G0l, G1h, G1l;
  {
    float g[16];
    #pragma unroll
    for (int ii = 0; ii < 16; ++ii) {
      const int i = 8*w + 16*(ii>>3) + (ii&7);
      g[ii] = Gs[lq*33 + i];
    }
    unsigned gh[8], gl[8];
    #pragma unroll
    for (int p = 0; p < 8; ++p) {
      float a = g[2*p], bb = g[2*p+1];
      _Float16 ha = (_Float16)a, hb = (_Float16)bb;
      gh[p] = (unsigned)__builtin_bit_cast(unsigned short, ha) |
              ((unsigned)__builtin_bit_cast(unsigned short, hb) << 16);
      gl[p] = pack_h2(a - (float)ha, bb - (float)hb);
    }
    G0h = frag4h(gh[0],gh[1],gh[2],gh[3]);
    G1h = frag4h(gh[4],gh[5],gh[6],gh[7]);
    G0l = frag4h(gl[0],gl[1],gl[2],gl[3]);
    G1l = frag4h(gl[4],gl[5],gl[6],gl[7]);
  }
  __syncthreads();   // LDS reused by merge

  f32x16 oacc;
  #pragma unroll
  for (int r = 0; r < 16; ++r) oacc[r] = 0.f;
  float m = -INFINITY, l = 0.f;

  const char* Ab = ws + OFF_A + (size_t)(b*16 + grp*4)*8192;
  const char* Tb = ws + OFF_T + (size_t)(b*16 + grp*4)*4096;
  const int lo16 = lane*16;

  #pragma unroll 2
  for (int j = 0; j < 4; ++j) {
    const char* A = Ab + j*8192;
    const char* T = Tb + j*4096;
    f16x8 ah0 = ldh(A + 0*1024 + lo16);
    f16x8 ah1 = ldh(A + 1*1024 + lo16);
    f16x8 ah2 = ldh(A + 2*1024 + lo16);
    f16x8 ah3 = ldh(A + 3*1024 + lo16);
    f16x8 al0 = ldh(A + 4096 + 0*1024 + lo16);
    f16x8 al1 = ldh(A + 4096 + 1*1024 + lo16);
    f16x8 al2 = ldh(A + 4096 + 2*1024 + lo16);
    f16x8 al3 = ldh(A + 4096 + 3*1024 + lo16);
    f16x8 at0 = ldh(T + 0*1024 + lo16);
    f16x8 at1 = ldh(T + 1*1024 + lo16);
    f16x8 at2 = ldh(T + 2*1024 + lo16);
    f16x8 at3 = ldh(T + 3*1024 + lo16);

    // ---- GEMM1: S^T[64k x 32q], 3-term fp16 split (exp2 domain) ----
    f32x16 sa0, sa1;
    #pragma unroll
    for (int r = 0; r < 16; ++r) { sa0[r] = 0.f; sa1[r] = 0.f; }
    sa0 = MFMA32H(ah0, G0h, sa0); sa0 = MFMA32H(ah0, G0l, sa0); sa0 = MFMA32H(al0, G0h, sa0);
    sa0 = MFMA32H(ah1, G1h, sa0); sa0 = MFMA32H(ah1, G1l, sa0); sa0 = MFMA32H(al1, G1h, sa0);
    sa1 = MFMA32H(ah2, G0h, sa1); sa1 = MFMA32H(ah2, G0l, sa1); sa1 = MFMA32H(al2, G0h, sa1);
    sa1 = MFMA32H(ah3, G1h, sa1); sa1 = MFMA32H(ah3, G1l, sa1); sa1 = MFMA32H(al3, G1h, sa1);

    // ---- online softmax: tree max, defer-max (8*log2e), tree sum ----
    float t0 = fmaxf(fmaxf(sa0[0], sa0[1]),  fmaxf(sa0[2],  sa0[3]));
    float t1 = fmaxf(fmaxf(sa0[4], sa0[5]),  fmaxf(sa0[6],  sa0[7]));
    float t2 = fmaxf(fmaxf(sa0[8], sa0[9]),  fmaxf(sa0[10], sa0[11]));
    float t3 = fmaxf(fmaxf(sa0[12],sa0[13]), fmaxf(sa0[14], sa0[15]));
    float t4 = fmaxf(fmaxf(sa1[0], sa1[1]),  fmaxf(sa1[2],  sa1[3]));
    float t5 = fmaxf(fmaxf(sa1[4], sa1[5]),  fmaxf(sa1[6],  sa1[7]));
    float t6 = fmaxf(fmaxf(sa1[8], sa1[9]),  fmaxf(sa1[10], sa1[11]));
    float t7 = fmaxf(fmaxf(sa1[12],sa1[13]), fmaxf(sa1[14], sa1[15]));
    float tm = fmaxf(fmaxf(fmaxf(t0,t1), fmaxf(t2,t3)),
                     fmaxf(fmaxf(t4,t5), fmaxf(t6,t7)));
    tm = cross_max(tm);
    if (!__all(tm - m <= 11.5415603f)) {    // = 8 * log2(e)
      float mn = fmaxf(m, tm);
      float alpha = ex2(m - mn);
      m = mn;
      l *= alpha;
      #pragma unroll
      for (int r = 0; r < 16; ++r) oacc[r] *= alpha;
    }
    #pragma unroll
    for (int r = 0; r < 16; ++r) { sa0[r] = ex2(sa0[r] - m); sa1[r] = ex2(sa1[r] - m); }
    float s0 = (sa0[0] + sa0[1])  + (sa0[2]  + sa0[3]);
    float s1 = (sa0[4] + sa0[5])  + (sa0[6]  + sa0[7]);
    float s2 = (sa0[8] + sa0[9])  + (sa0[10] + sa0[11]);
    float s3 = (sa0[12]+ sa0[13]) + (sa0[14] + sa0[15]);
    float s4 = (sa1[0] + sa1[1])  + (sa1[2]  + sa1[3]);
    float s5 = (sa1[4] + sa1[5])  + (sa1[6]  + sa1[7]);
    float s6 = (sa1[8] + sa1[9])  + (sa1[10] + sa1[11]);
    float s7 = (sa1[12]+ sa1[13]) + (sa1[14] + sa1[15]);
    float ps = ((s0+s1) + (s2+s3)) + ((s4+s5) + (s6+s7));
    ps = cross_add(ps);
    l += ps;

    // ---- GEMM2: O^T += xkT * P (dst=low-pair) ----
    {
      unsigned u0 = pkh(sa0[0], sa0[1]),  u1 = pkh(sa0[2], sa0[3]);
      unsigned v0 = pkh(sa0[4], sa0[5]),  v1 = pkh(sa0[6], sa0[7]);
      plswap(u0, v0); plswap(u1, v1);
      oacc = MFMA32H(at0, frag4h(u0, u1, v0, v1), oacc);

      unsigned u2 = pkh(sa0[8], sa0[9]),   u3 = pkh(sa0[10], sa0[11]);
      unsigned v2 = pkh(sa0[12], sa0[13]), v3 = pkh(sa0[14], sa0[15]);
      plswap(u2, v2); plswap(u3, v3);
      oacc = MFMA32H(at1, frag4h(u2, u3, v2, v3), oacc);

      unsigned u4 = pkh(sa1[0], sa1[1]),  u5 = pkh(sa1[2], sa1[3]);
      unsigned v4 = pkh(sa1[4], sa1[5]),  v5 = pkh(sa1[6], sa1[7]);
      plswap(u4, v4); plswap(u5, v5);
      oacc = MFMA32H(at2, frag4h(u4, u5, v4, v5), oacc);

      unsigned u6 = pkh(sa1[8], sa1[9]),   u7 = pkh(sa1[10], sa1[11]);
      unsigned v6 = pkh(sa1[12], sa1[13]), v7 = pkh(sa1[14], sa1[15]);
      plswap(u6, v6); plswap(u7, v7);
      oacc = MFMA32H(at3, frag4h(u6, u7, v6, v7), oacc);
    }
  }

  // ---- 4-way flash-merge across waves (symmetric, exp2 domain) ----
  {
    float* ms = (float*)(smem + ((wid<<6) | lane) * 80);
    *(float4*)(ms + 0)  = (float4){oacc[0],  oacc[1],  oacc[2],  oacc[3]};
    *(float4*)(ms + 4)  = (float4){oacc[4],  oacc[5],  oacc[6],  oacc[7]};
    *(float4*)(ms + 8)  = (float4){oacc[8],  oacc[9],  oacc[10], oacc[11]};
    *(float4*)(ms + 12) = (float4){oacc[12], oacc[13], oacc[14], oacc[15]};
    ms[16] = m; ms[17] = l;
    __syncthreads();
    #pragma unroll
    for (int og = 0; og < 4; ++og) {
      if (og == wid) continue;
      const float* pp = (const float*)(smem + ((og<<6) | lane) * 80);
      float4 p0 = *(const float4*)(pp + 0);
      float4 p1 = *(const float4*)(pp + 4);
      float4 p2 = *(const float4*)(pp + 8);
      float4 p3 = *(const float4*)(pp + 12);
      float pm = pp[16], pl = pp[17];
      float mf = fmaxf(m, pm);
      float as = ex2(m - mf), ap = ex2(pm - mf);
      l = l * as + pl * ap;
      float po[16] = {p0.x,p0.y,p0.z,p0.w, p1.x,p1.y,p1.z,p1.w,
                      p2.x,p2.y,p2.z,p2.w, p3.x,p3.y,p3.z,p3.w};
      #pragma unroll
      for (int r = 0; r < 16; ++r) oacc[r] = oacc[r] * as + po[r] * ap;
      m = mf;
    }
    __syncthreads();   // before zb reuse of this region
  }

  // ---- epilogue: Z^T = WvT * O_norm; wave handles mt = wid*2 + {0,1} ----
  float inv = 1.0f / (16.0f * l);
  #pragma unroll
  for (int r = 0; r < 16; ++r) oacc[r] *= inv;
  f16x8 of0, of1;
  {
    unsigned u0 = pkh(oacc[0], oacc[1]),  u1 = pkh(oacc[2], oacc[3]);
    unsigned v0 = pkh(oacc[4], oacc[5]),  v1 = pkh(oacc[6], oacc[7]);
    plswap(u0, v0); plswap(u1, v1);
    of0 = frag4h(u0, u1, v0, v1);
    unsigned u2 = pkh(oacc[8], oacc[9]),   u3 = pkh(oacc[10], oacc[11]);
    unsigned v2 = pkh(oacc[12], oacc[13]), v3 = pkh(oacc[14], oacc[15]);
    plswap(u2, v2); plswap(u3, v3);
    of1 = frag4h(u2, u3, v2, v3);
  }
  const char* WvTb = ws + OFF_WVT;
  float* zb = (float*)(smem + wid * 4224);
  const size_t orow = ((size_t)b * SEQ + q0);
  #pragma unroll 1
  for (int mi = 0; mi < 2; ++mi) {
    const int mt = wid*2 + mi;
    const char* wp = WvTb + (mt*32 + lq)*64 + 16*w;
    f16x8 a0 = ldh(wp);
    f16x8 a1 = ldh(wp + 32);
    f32x16 z;
    #pragma unroll
    for (int r = 0; r < 16; ++r) z[r] = 0.f;
    z = MFMA32H(a0, of0, z);
    z = MFMA32H(a1, of1, z);
    #pragma unroll
    for (int r = 0; r < 16; ++r) {
      int hl = (r&3) + 8*(r>>2) + 4*w;
      zb[hl*33 + lq] = z[r];
    }
    asm volatile("s_waitcnt lgkmcnt(0)" ::: "memory");
    float bvv = bv[mt*32 + lq] * 0.0625f;
    #pragma unroll
    for (int jj = 0; jj < 16; ++jj) {
      int q = w*16 + jj;
      out[(orow + q)*HID + mt*32 + lq] = zb[lq*33 + q] + bvv;
    }
    asm volatile("s_waitcnt lgkmcnt(0)" ::: "memory");
  }
}

// ====================== FALLBACK (round-6, proven) ======================

__global__ void precompute_kernel(const float* __restrict__ Wq, const float* __restrict__ Wk,
                                  const float* __restrict__ bq, const float* __restrict__ Wv,
                                  float* __restrict__ ws) {
  const int gid = blockIdx.x * 256 + threadIdx.x;
  if (gid < 1024) {
    int i = gid >> 5, j = gid & 31;
    const float* a  = Wq + j * HID;
    const float* b2 = Wk + i * HID;
    float a0=0.f,a1=0.f,a2=0.f,a3=0.f;
    for (int h = 0; h < HID; h += 8) {
      float4 x1 = *(const float4*)(a + h),  y1 = *(const float4*)(b2 + h);
      float4 x2 = *(const float4*)(a + h+4), y2 = *(const float4*)(b2 + h+4);
      a0 = fmaf(x1.x,y1.x,a0); a1 = fmaf(x1.y,y1.y,a1);
      a2 = fmaf(x1.z,y1.z,a2); a3 = fmaf(x1.w,y1.w,a3);
      a0 = fmaf(x2.x,y2.x,a0); a1 = fmaf(x2.y,y2.y,a1);
      a2 = fmaf(x2.z,y2.z,a2); a3 = fmaf(x2.w,y2.w,a3);
    }
    ws[gid] = (a0+a1)+(a2+a3);
  } else if (gid < 1056) {
    int i2 = gid - 1024;
    const float* b2 = Wk + i2 * HID;
    float acc = 0.f;
    for (int h = 0; h < HID; ++h) acc = fmaf(b2[h], bq[h], acc);
    ws[1024 + i2] = acc;
  } else if (gid < 1056 + HID*16) {
    int e = gid - 1056;
    int h = e >> 4, d = e & 15;
    ((unsigned*)((char*)ws + 4224))[e] = pk_bf16(Wv[(2*d)*HID + h], Wv[(2*d+1)*HID + h]);
  }
}

__global__ __launch_bounds__(512, 4) void attn_kernel(
    const float* __restrict__ x, const float* __restrict__ ws,
    const float* __restrict__ bv, float* __restrict__ out) {
  __shared__ __align__(16) char smem[SMEM_SZ];
  const int b    = blockIdx.y;
  const int q0   = blockIdx.x * QT;
  const int t    = threadIdx.x;
  const int grp  = t >> 8;
  const int ts   = t & 255;
  const int wid  = t >> 6;
  const int wq   = wid & 3;
  const int lane = t & 63;
  const int w    = lane >> 5;
  const int lq   = lane & 31;
  const float* xb = x + (size_t)b * SEQ * DIN;

  float* ATs = (float*)(smem + ATS_OFF);
  for (int e = t; e < 1056; e += 512) ATs[e] = ws[e];

  {
    const int sb = SETB(grp, 0);
    const int r = ts >> 2, s4 = ts & 3;
    const float* src = xb + (size_t)(grp * KT + r) * DIN + s4 * 8;
    float4 va = *(const float4*)src;
    float4 vb = *(const float4*)(src + 4);
    unsigned h0 = bf16_hi_bits(va.x) | (bf16_hi_bits(va.y) << 16);
    unsigned h1 = bf16_hi_bits(va.z) | (bf16_hi_bits(va.w) << 16);
    unsigned h2 = bf16_hi_bits(vb.x) | (bf16_hi_bits(vb.y) << 16);
    unsigned h3 = bf16_hi_bits(vb.z) | (bf16_hi_bits(vb.w) << 16);
    unsigned l0 = bf16_hi_bits(va.x - __uint_as_float(h0<<16)) | (bf16_hi_bits(va.y - __uint_as_float(h0 & 0xffff0000u)) << 16);
    unsigned l1 = bf16_hi_bits(va.z - __uint_as_float(h1<<16)) | (bf16_hi_bits(va.w - __uint_as_float(h1 & 0xffff0000u)) << 16);
    unsigned l2 = bf16_hi_bits(vb.x - __uint_as_float(h2<<16)) | (bf16_hi_bits(vb.y - __uint_as_float(h2 & 0xffff0000u)) << 16);
    unsigned l3 = bf16_hi_bits(vb.z - __uint_as_float(h3<<16)) | (bf16_hi_bits(vb.w - __uint_as_float(h3 & 0xffff0000u)) << 16);
    int off = r*64 + ((s4 ^ (r & 3)) << 4);
    *(u32x4v*)(smem + sb + off)        = (u32x4v){h0,h1,h2,h3};
    *(u32x4v*)(smem + sb + 4096 + off) = (u32x4v){l0,l1,l2,l3};
    const int ci = ts & 31, cr = (ts >> 5) * 8;
    const float* cs = xb + (size_t)(grp * KT + cr) * DIN + ci;
    float c0=cs[0], c1=cs[DIN], c2=cs[2*DIN], c3=cs[3*DIN];
    float c4=cs[4*DIN], c5=cs[5*DIN], c6=cs[6*DIN], c7=cs[7*DIN];
    unsigned t0 = pk_bf16(c0,c1), t1 = pk_bf16(c2,c3), t2 = pk_bf16(c4,c5), t3 = pk_bf16(c6,c7);
    int toff = sb + 8192 + ci*128 + (((ts>>5) ^ (ci & 7)) << 4);
    *(u32x4v*)(smem + toff) = (u32x4v){t0,t1,t2,t3};
  }
  __syncthreads();

  float g[16];
  {
    float xq[32];
    const float* xrow = xb + (size_t)(q0 + wq*32 + lq) * DIN;
    #pragma unroll
    for (int c = 0; c < 8; ++c) {
      float4 v = *(const float4*)(xrow + c*4);
      xq[c*4+0]=v.x; xq[c*4+1]=v.y; xq[c*4+2]=v.z; xq[c*4+3]=v.w;
    }
    #pragma unroll
    for (int ii = 0; ii < 16; ++ii) {
      const int i = 8*w + 16*(ii>>3) + (ii&7);
      const float* ar = ATs + i*32;
      float acc = ATs[1024 + i];
      #pragma unroll
      for (int j = 0; j < 8; ++j) {
        float4 av = *(const float4*)(ar + j*4);
        acc = fmaf(xq[j*4+0], av.x, acc);
        acc = fmaf(xq[j*4+1], av.y, acc);
        acc = fmaf(xq[j*4+2], av.z, acc);
        acc = fmaf(xq[j*4+3], av.w, acc);
      }
      g[ii] = acc;
    }
  }
  s16x8 G0h, G0l, G1h, G1l;
  {
    unsigned gh[2][4], gl[2][4];
    #pragma unroll
    for (int Ks = 0; Ks < 2; ++Ks)
      #pragma unroll
      for (int d = 0; d < 4; ++d) {
        float ga = g[Ks*8 + 2*d], gb = g[Ks*8 + 2*d + 1];
        unsigned hp = bf16_hi_bits(ga) | (bf16_hi_bits(gb) << 16);
        unsigned lp = bf16_hi_bits(ga - __uint_as_float(hp<<16)) |
                      (bf16_hi_bits(gb - __uint_as_float(hp & 0xffff0000u)) << 16);
        gh[Ks][d] = hp; gl[Ks][d] = lp;
      }
    G0h = frag4(gh[0][0],gh[0][1],gh[0][2],gh[0][3]);
    G0l = frag4(gl[0][0],gl[0][1],gl[0][2],gl[0][3]);
    G1h = frag4(gh[1][0],gh[1][1],gh[1][2],gh[1][3]);
    G1l = frag4(gl[1][0],gl[1][1],gl[1][2],gl[1][3]);
  }

  f32x16 oacc;
  #pragma unroll
  for (int r = 0; r < 16; ++r) oacc[r] = 0.f;
  float m = -INFINITY, l = 0.f;

  for (int j = 0; j < NKT/2; ++j) {
    const bool hn = (j + 1 < NKT/2);
    float4 va, vb;
    float c0=0,c1=0,c2=0,c3=0,c4=0,c5=0,c6=0,c7=0;
    if (hn) {
      const int ktn = 2*(j+1) + grp;
      const int r = ts >> 2, s4 = ts & 3;
      const float* src = xb + (size_t)(ktn*KT + r) * DIN + s4*8;
      va = *(const float4*)src;
      vb = *(const float4*)(src + 4);
      const int ci = ts & 31, cr = (ts >> 5) * 8;
      const float* cs = xb + (size_t)(ktn*KT + cr) * DIN + ci;
      c0=cs[0]; c1=cs[DIN]; c2=cs[2*DIN]; c3=cs[3*DIN];
      c4=cs[4*DIN]; c5=cs[5*DIN]; c6=cs[6*DIN]; c7=cs[7*DIN];
    }

    const int sb = SETB(grp, j & 1);
    const char* bh = smem + sb;
    const char* bl = smem + sb + 4096;
    const int co0 = ((w    ) ^ (lq & 3)) << 4;
    const int co1 = ((w + 2) ^ (lq & 3)) << 4;
    s16x8 ah00 = *(const s16x8*)(bh + lq*64 + co0);
    s16x8 ah01 = *(const s16x8*)(bh + lq*64 + co1);
    s16x8 al00 = *(const s16x8*)(bl + lq*64 + co0);
    s16x8 al01 = *(const s16x8*)(bl + lq*64 + co1);
    s16x8 ah10 = *(const s16x8*)(bh + (32+lq)*64 + co0);
    s16x8 ah11 = *(const s16x8*)(bh + (32+lq)*64 + co1);
    s16x8 al10 = *(const s16x8*)(bl + (32+lq)*64 + co0);
    s16x8 al11 = *(const s16x8*)(bl + (32+lq)*64 + co1);
    f32x16 sa0, sa1;
    #pragma unroll
    for (int r = 0; r < 16; ++r) { sa0[r] = 0.f; sa1[r] = 0.f; }
    sa0 = MFMA32(ah00, G0h, sa0); sa0 = MFMA32(ah00, G0l, sa0); sa0 = MFMA32(al00, G0h, sa0);
    sa0 = MFMA32(ah01, G1h, sa0); sa0 = MFMA32(ah01, G1l, sa0); sa0 = MFMA32(al01, G1h, sa0);
    sa1 = MFMA32(ah10, G0h, sa1); sa1 = MFMA32(ah10, G0l, sa1); sa1 = MFMA32(al10, G0h, sa1);
    sa1 = MFMA32(ah11, G1h, sa1); sa1 = MFMA32(ah11, G1l, sa1); sa1 = MFMA32(al11, G1h, sa1);

    float tm = sa0[0];
    #pragma unroll
    for (int r = 1; r < 16; ++r) tm = fmaxf(tm, sa0[r]);
    #pragma unroll
    for (int r = 0; r < 16; ++r) tm = fmaxf(tm, sa1[r]);
    tm = cross_max(tm);
    float mn = fmaxf(m, tm);
    float alpha = __expf(m - mn);
    m = mn;
    float ps = 0.f;
    #pragma unroll
    for (int r = 0; r < 16; ++r) { float p = __expf(sa0[r] - mn); sa0[r] = p; ps += p; }
    #pragma unroll
    for (int r = 0; r < 16; ++r) { float p = __expf(sa1[r] - mn); sa1[r] = p; ps += p; }
    ps = cross_add(ps);
    l = l * alpha + ps;
    #pragma unroll
    for (int r = 0; r < 16; ++r) oacc[r] *= alpha;

    const char* bt = smem + sb + 8192;
    {
      unsigned u0 = pk_bf16(sa0[0], sa0[1]),  u1 = pk_bf16(sa0[2], sa0[3]);
      unsigned v0 = pk_bf16(sa0[4], sa0[5]),  v1 = pk_bf16(sa0[6], sa0[7]);
      plswap(u0, v0); plswap(u1, v1);
      s16x8 at0 = *(const s16x8*)(bt + lq*128 + (((0 + w) ^ (lq & 7)) << 4));
      oacc = MFMA32(at0, frag4(u0, u1, v0, v1), oacc);

      unsigned u2 = pk_bf16(sa0[8], sa0[9]),   u3 = pk_bf16(sa0[10], sa0[11]);
      unsigned v2 = pk_bf16(sa0[12], sa0[13]), v3 = pk_bf16(sa0[14], sa0[15]);
      plswap(u2, v2); plswap(u3, v3);
      s16x8 at1 = *(const s16x8*)(bt + lq*128 + (((2 + w) ^ (lq & 7)) << 4));
      oacc = MFMA32(at1, frag4(u2, u3, v2, v3), oacc);

      unsigned u4 = pk_bf16(sa1[0], sa1[1]),  u5 = pk_bf16(sa1[2], sa1[3]);
      unsigned v4 = pk_bf16(sa1[4], sa1[5]),  v5 = pk_bf16(sa1[6], sa1[7]);
      plswap(u4, v4); plswap(u5, v5);
      s16x8 at2 = *(const s16x8*)(bt + lq*128 + (((4 + w) ^ (lq & 7)) << 4));
      oacc = MFMA32(at2, frag4(u4, u5, v4, v5), oacc);

      unsigned u6 = pk_bf16(sa1[8], sa1[9]),   u7 = pk_bf16(sa1[10], sa1[11]);
      unsigned v6 = pk_bf16(sa1[12], sa1[13]), v7 = pk_bf16(sa1[14], sa1[15]);
      plswap(u6, v6); plswap(u7, v7);
      s16x8 at3 = *(const s16x8*)(bt + lq*128 + (((6 + w) ^ (lq & 7)) << 4));
      oacc = MFMA32(at3, frag4(u6, u7, v6, v7), oacc);
    }

    if (hn) {
      const int nsb = SETB(grp, (j+1) & 1);
      const int r = ts >> 2, s4 = ts & 3;
      unsigned h0 = bf16_hi_bits(va.x) | (bf16_hi_bits(va.y) << 16);
      unsigned h1 = bf16_hi_bits(va.z) | (bf16_hi_bits(va.w) << 16);
      unsigned h2 = bf16_hi_bits(vb.x) | (bf16_hi_bits(vb.y) << 16);
      unsigned h3 = bf16_hi_bits(vb.z) | (bf16_hi_bits(vb.w) << 16);
      unsigned l0 = bf16_hi_bits(va.x - __uint_as_float(h0<<16)) | (bf16_hi_bits(va.y - __uint_as_float(h0 & 0xffff0000u)) << 16);
      unsigned l1 = bf16_hi_bits(va.z - __uint_as_float(h1<<16)) | (bf16_hi_bits(va.w - __uint_as_float(h1 & 0xffff0000u)) << 16);
      unsigned l2 = bf16_hi_bits(vb.x - __uint_as_float(h2<<16)) | (bf16_hi_bits(vb.y - __uint_as_float(h2 & 0xffff0000u)) << 16);
      unsigned l3 = bf16_hi_bits(vb.z - __uint_as_float(h3<<16)) | (bf16_hi_bits(vb.w - __uint_as_float(h3 & 0xffff0000u)) << 16);
      int off = r*64 + ((s4 ^ (r & 3)) << 4);
      *(u32x4v*)(smem + nsb + off)        = (u32x4v){h0,h1,h2,h3};
      *(u32x4v*)(smem + nsb + 4096 + off) = (u32x4v){l0,l1,l2,l3};
      const int ci = ts & 31;
      unsigned t0 = pk_bf16(c0,c1), t1 = pk_bf16(c2,c3), t2 = pk_bf16(c4,c5), t3 = pk_bf16(c6,c7);
      int toff = nsb + 8192 + ci*128 + (((ts>>5) ^ (ci & 7)) << 4);
      *(u32x4v*)(smem + toff) = (u32x4v){t0,t1,t2,t3};
    }
    __syncthreads();
  }

  {
    float* ms = (float*)(smem + grp*20480 + (((wq<<6) | lane) * 80));
    *(float4*)(ms + 0)  = (float4){oacc[0],  oacc[1],  oacc[2],  oacc[3]};
    *(float4*)(ms + 4)  = (float4){oacc[4],  oacc[5],  oacc[6],  oacc[7]};
    *(float4*)(ms + 8)  = (float4){oacc[8],  oacc[9],  oacc[10], oacc[11]};
    *(float4*)(ms + 12) = (float4){oacc[12], oacc[13], oacc[14], oacc[15]};
    ms[16] = m; ms[17] = l;
    __syncthreads();
    const float* pp = (const float*)(smem + (1-grp)*20480 + (((wq<<6) | lane) * 80));
    float4 p0 = *(const float4*)(pp + 0);
    float4 p1 = *(const float4*)(pp + 4);
    float4 p2 = *(const float4*)(pp + 8);
    float4 p3 = *(const float4*)(pp + 12);
    float pm = pp[16], pl = pp[17];
    float mf = fmaxf(m, pm);
    float as = __expf(m - mf), ap = __expf(pm - mf);
    l = l * as + pl * ap;
    float po[16] = {p0.x,p0.y,p0.z,p0.w, p1.x,p1.y,p1.z,p1.w,
                    p2.x,p2.y,p2.z,p2.w, p3.x,p3.y,p3.z,p3.w};
    #pragma unroll
    for (int r = 0; r < 16; ++r) oacc[r] = oacc[r] * as + po[r] * ap;
    __syncthreads();
  }

  float inv = 1.0f / (16.0f * l);
  #pragma unroll
  for (int r = 0; r < 16; ++r) oacc[r] *= inv;
  s16x8 of0, of1;
  {
    unsigned u0 = pk_bf16(oacc[0], oacc[1]),  u1 = pk_bf16(oacc[2], oacc[3]);
    unsigned v0 = pk_bf16(oacc[4], oacc[5]),  v1 = pk_bf16(oacc[6], oacc[7]);
    plswap(u0, v0); plswap(u1, v1);
    of0 = frag4(u0, u1, v0, v1);
    unsigned u2 = pk_bf16(oacc[8], oacc[9]),   u3 = pk_bf16(oacc[10], oacc[11]);
    unsigned v2 = pk_bf16(oacc[12], oacc[13]), v3 = pk_bf16(oacc[14], oacc[15]);
    plswap(u2, v2); plswap(u3, v3);
    of1 = frag4(u2, u3, v2, v3);
  }
  const char* WvTb = (const char*)ws + 4224;
  float* zb = (float*)(smem + wid * 4224);
  const size_t orow = ((size_t)b * SEQ + q0 + wq*32);
  #pragma unroll 1
  for (int mi = 0; mi < 4; ++mi) {
    const int mt = grp*4 + mi;
    const char* wp = WvTb + (mt*32 + lq)*64 + 16*w;
    s16x8 a0 = *(const s16x8*)wp;
    s16x8 a1 = *(const s16x8*)(wp + 32);
    f32x16 z;
    #pragma unroll
    for (int r = 0; r < 16; ++r) z[r] = 0.f;
    z = MFMA32(a0, of0, z);
    z = MFMA32(a1, of1, z);
    #pragma unroll
    for (int r = 0; r < 16; ++r) {
      int hl = (r&3) + 8*(r>>2) + 4*w;
      zb[hl*33 + lq] = z[r];
    }
    asm volatile("s_waitcnt lgkmcnt(0)" ::: "memory");
    float bvv = bv[mt*32 + lq] * 0.0625f;
    #pragma unroll
    for (int jj = 0; jj < 16; ++jj) {
      int q = w*16 + jj;
      out[(orow + q)*HID + mt*32 + lq] = zb[lq*33 + q] + bvv;
    }
    asm volatile("s_waitcnt lgkmcnt(0)" ::: "memory");
  }
}

extern "C" void kernel_launch(void* const* d_in, const int* in_sizes, int n_in,
                              void* d_out, int out_size, void* d_ws, size_t ws_size,
                              hipStream_t stream) {
  (void)in_sizes; (void)n_in; (void)out_size;
  const float* x  = (const float*)d_in[0];
  const float* Wq = (const float*)d_in[1];
  const float* bq = (const float*)d_in[2];
  const float* Wk = (const float*)d_in[3];
  const float* Wv = (const float*)d_in[5];
  const float* bv = (const float*)d_in[6];
  float* out = (float*)d_out;
  float* ws  = (float*)d_ws;

  if (ws_size >= WS_NEED) {
    pack2_kernel<<<1048, 256, 0, stream>>>(x, Wq, Wk, bq, Wv, (char*)ws);
    attn_fast<<<2048, 256, 0, stream>>>(x, (const char*)ws, bv, out);
  } else {
    precompute_kernel<<<24, 256, 0, stream>>>(Wq, Wk, bq, Wv, ws);
    attn_kernel<<<dim3(SEQ/QT, NB), 512, 0, stream>>>(x, ws, bv, out);
  }
}

// Round 19
// 57.908 us; speedup vs baseline: 1.2602x; 1.0026x over previous
//
#include <hip/hip_runtime.h>
#include <math.h>

#define NB   64
#define SEQ  1024
#define DIN  32
#define HID  256
#define QT   128
#define KT   64
#define NKT  (SEQ/KT)
#define LOG2E 1.4426950408889634f

typedef float        f32x16 __attribute__((ext_vector_type(16)));
typedef short        s16x8  __attribute__((ext_vector_type(8)));
typedef _Float16     f16x8  __attribute__((ext_vector_type(8)));
typedef unsigned int u32x4v __attribute__((ext_vector_type(4)));
typedef unsigned int u32x2v __attribute__((ext_vector_type(2)));

#define MFMA32(A,B,C)  __builtin_amdgcn_mfma_f32_32x32x16_bf16(A,B,C,0,0,0)
#define MFMA32H(A,B,C) __builtin_amdgcn_mfma_f32_32x32x16_f16(A,B,C,0,0,0)

// ---- ws byte offsets (fast path) ----
// ws[0..1055] f32: AT[32][32]*log2e + u[32]*log2e; OFF_WVT: u32[4096] WvT fp16.
#define OFF_WVT  4224
#define OFF_A    24576                      // [64*16][8192] A-frags hi|lo
#define OFF_T    (OFF_A + 64*16*8192)       // [64*16][4096] xkT-frags hi
#define WS_NEED  ((size_t)OFF_T + 64*16*4096)

// fallback LDS map
#define SETB(g,p) (((g)*2+(p))*12288)
#define ATS_OFF   49152
#define SMEM_SZ   (ATS_OFF + 4224)

__device__ __forceinline__ float ex2(float v) {      // 2^v, raw v_exp_f32
  return __builtin_amdgcn_exp2f(v);
}
__device__ __forceinline__ unsigned pk_bf16(float lo, float hi) {
  unsigned r;
  asm("v_cvt_pk_bf16_f32 %0, %1, %2" : "=v"(r) : "v"(lo), "v"(hi));
  return r;
}
__device__ __forceinline__ unsigned pkh(float a, float b) {
  return __builtin_bit_cast(unsigned, __builtin_amdgcn_cvt_pkrtz(a, b));
}
// new_dst = [dst.lo(lanes<32) | src.lo], new_src = [dst.hi | src.hi]
__device__ __forceinline__ void plswap(unsigned &vdst, unsigned &vsrc) {
  u32x2v r = __builtin_amdgcn_permlane32_swap(vdst, vsrc, false, false);
  vdst = r[0]; vsrc = r[1];
}
__device__ __forceinline__ float cross_max(float v) {
  u32x2v r = __builtin_amdgcn_permlane32_swap(__float_as_uint(v), __float_as_uint(v), false, false);
  return fmaxf(__uint_as_float(r[0]), __uint_as_float(r[1]));
}
__device__ __forceinline__ float cross_add(float v) {
  u32x2v r = __builtin_amdgcn_permlane32_swap(__float_as_uint(v), __float_as_uint(v), false, false);
  return __uint_as_float(r[0]) + __uint_as_float(r[1]);
}
__device__ __forceinline__ s16x8 frag4(unsigned a, unsigned b, unsigned c, unsigned d) {
  u32x4v t; t[0]=a; t[1]=b; t[2]=c; t[3]=d;
  return __builtin_bit_cast(s16x8, t);
}
__device__ __forceinline__ f16x8 frag4h(unsigned a, unsigned b, unsigned c, unsigned d) {
  u32x4v t; t[0]=a; t[1]=b; t[2]=c; t[3]=d;
  return __builtin_bit_cast(f16x8, t);
}
__device__ __forceinline__ f16x8 ldh(const void* p) {
  return __builtin_bit_cast(f16x8, *(const u32x4v*)p);
}
__device__ __forceinline__ unsigned bf16_hi_bits(float f) {
  unsigned ux = __float_as_uint(f);
  return (ux + 0x7fffu + ((ux >> 16) & 1u)) >> 16;
}
__device__ __forceinline__ unsigned pack_h2(float a, float b) {
  _Float16 ha = (_Float16)a, hb = (_Float16)b;
  return (unsigned)__builtin_bit_cast(unsigned short, ha) |
         ((unsigned)__builtin_bit_cast(unsigned short, hb) << 16);
}

// ====================== FAST PATH (round-15 proven best: 58.2us) ======================

// Pack kernel, 1048 blocks:
//  [0,1024): one (b,kt) tile — coalesced x load -> padded LDS -> A/T frags.
//  [1024,1048): AT*log2e + u*log2e (ONCE) and WvT fp16 pairs.
__global__ __launch_bounds__(256) void pack2_kernel(
    const float* __restrict__ x,
    const float* __restrict__ Wq, const float* __restrict__ Wk,
    const float* __restrict__ bq, const float* __restrict__ Wv,
    char* __restrict__ ws) {
  __shared__ float xs[64 * 33];   // stride 33: kills column-read bank conflicts
  const int bid = blockIdx.x;
  const int t   = threadIdx.x;
  if (bid < 1024) {
    const int b = bid >> 4, kt = bid & 15;
    {
      const int r = t >> 2, c = (t & 3) * 8;
      const float* src = x + ((size_t)(b*SEQ + kt*KT + r))*DIN + c;
      float4 v0 = *(const float4*)src, v1 = *(const float4*)(src + 4);
      float* d = xs + r*33 + c;
      d[0]=v0.x; d[1]=v0.y; d[2]=v0.z; d[3]=v0.w;
      d[4]=v1.x; d[5]=v1.y; d[6]=v1.z; d[7]=v1.w;
    }
    __syncthreads();
    const int l = t & 63, f = t >> 6;
    const int w = l >> 5, lq = l & 31;
    // ---- A fragment (hi/lo fp16) ----
    {
      const int row = ((f&2)?32:0) + lq;
      const int d0  = ((f&1)?16:0) + 8*w;
      const float* vsrc = xs + row*33 + d0;
      unsigned hi[4], lo[4];
      #pragma unroll
      for (int j = 0; j < 4; ++j) {
        float a = vsrc[2*j], c2 = vsrc[2*j+1];
        _Float16 ha = (_Float16)a, hb = (_Float16)c2;
        hi[j] = (unsigned)__builtin_bit_cast(unsigned short, ha) |
                ((unsigned)__builtin_bit_cast(unsigned short, hb) << 16);
        lo[j] = pack_h2(a - (float)ha, c2 - (float)hb);
      }
      char* dst = ws + OFF_A + (size_t)bid*8192 + f*1024 + l*16;
      *(u32x4v*)dst          = (u32x4v){hi[0],hi[1],hi[2],hi[3]};
      *(u32x4v*)(dst + 4096) = (u32x4v){lo[0],lo[1],lo[2],lo[3]};
    }
    // ---- T fragment (hi fp16) ----
    {
      const int k0 = 16*f + 8*w;
      unsigned hi[4];
      #pragma unroll
      for (int j = 0; j < 4; ++j)
        hi[j] = pack_h2(xs[(k0 + 2*j)*33 + lq], xs[(k0 + 2*j + 1)*33 + lq]);
      char* dst = ws + OFF_T + (size_t)bid*4096 + f*1024 + l*16;
      *(u32x4v*)dst = (u32x4v){hi[0],hi[1],hi[2],hi[3]};
    }
  } else {
    const int gid = (bid - 1024) * 256 + t;
    float* wsf = (float*)ws;
    if (gid < 1024) {
      int i = gid >> 5, j = gid & 31;
      const float* a  = Wq + j * HID;
      const float* b2 = Wk + i * HID;
      float a0=0.f,a1=0.f,a2=0.f,a3=0.f;
      for (int h = 0; h < HID; h += 8) {
        float4 x1 = *(const float4*)(a + h),  y1 = *(const float4*)(b2 + h);
        float4 x2 = *(const float4*)(a + h+4), y2 = *(const float4*)(b2 + h+4);
        a0 = fmaf(x1.x,y1.x,a0); a1 = fmaf(x1.y,y1.y,a1);
        a2 = fmaf(x1.z,y1.z,a2); a3 = fmaf(x1.w,y1.w,a3);
        a0 = fmaf(x2.x,y2.x,a0); a1 = fmaf(x2.y,y2.y,a1);
        a2 = fmaf(x2.z,y2.z,a2); a3 = fmaf(x2.w,y2.w,a3);
      }
      wsf[gid] = ((a0+a1)+(a2+a3)) * LOG2E;   // exp2 domain
    } else if (gid < 1056) {
      int i2 = gid - 1024;
      const float* b2 = Wk + i2 * HID;
      float acc = 0.f;
      for (int h = 0; h < HID; ++h) acc = fmaf(b2[h], bq[h], acc);
      wsf[1024 + i2] = acc * LOG2E;           // exp2 domain
    } else if (gid < 1056 + HID*16) {
      int e = gid - 1056;
      int h = e >> 4, d = e & 15;
      ((unsigned*)(ws + OFF_WVT))[e] = pkh(Wv[(2*d)*HID + h], Wv[(2*d+1)*HID + h]);
    }
  }
}

// 2048 blocks x 256 threads = 4 waves = 4 k-groups over ONE 32-q subtile.
// Cooperative G'; exp2-domain softmax; barrier-free main loop (unroll 2,
// all frag loads at top of body); 4-way merge; epilogue 2 mt/wave.
// NOTE (r16/r17 lessons): XCD-remap of pack DOUBLED re-fetch (dispatch->XCD
// undefined); register double-buffer spilled at pinned VGPR=64 (80MB scratch).
// This r15 configuration is the measured optimum: 43.9us, FETCH 10.4MB.
__global__ __launch_bounds__(256, 4) void attn_fast(
    const float* __restrict__ x, const char* __restrict__ ws,
    const float* __restrict__ bv, float* __restrict__ out) {
  __shared__ __align__(16) char smem[20480];
  const int bid = blockIdx.x;
  const int vid = (bid & 7) * 256 + (bid >> 3);   // 2048 = 8 XCD * 256
  const int b   = vid >> 5;
  const int q0  = (vid & 31) * 32;
  const int t = threadIdx.x;
  const int wid = t>>6, lane = t&63, w = lane>>5, lq = lane&31;
  const int grp = wid;

  // ---- prologue: AT(+u) -> LDS (pad 33); cooperative G' -> LDS ----
  float* ATs = (float*)smem;               // [32][33] + u @1056..1087
  float* Gs  = (float*)(smem + 4480);      // [32][33]
  {
    const float* wsf = (const float*)ws;
    for (int e = t; e < 1024; e += 256) ATs[(e>>5)*33 + (e&31)] = wsf[e];
    if (t < 32) ATs[1056 + t] = wsf[1024 + t];
  }
  __syncthreads();
  {
    const int q = t >> 3, i0 = (t & 7) * 4;
    float xq[32];
    const float* xrow = x + (size_t)(b*SEQ + q0 + q) * DIN;
    #pragma unroll
    for (int c = 0; c < 8; ++c) {
      float4 v = *(const float4*)(xrow + c*4);
      xq[c*4+0]=v.x; xq[c*4+1]=v.y; xq[c*4+2]=v.z; xq[c*4+3]=v.w;
    }
    #pragma unroll
    for (int jo = 0; jo < 4; ++jo) {
      const int i = i0 + jo;
      const float* ar = ATs + i*33;
      float acc = ATs[1056 + i];
      #pragma unroll
      for (int j = 0; j < 32; ++j) acc = fmaf(xq[j], ar[j], acc);
      Gs[q*33 + i] = acc;
    }
  }
  __syncthreads();
  f16x8 G0h, G0l, G1h, G1l;
  {
    float g[16];
    #pragma unroll
    for (int ii = 0; ii < 16; ++ii) {
      const int i = 8*w + 16*(ii>>3) + (ii&7);
      g[ii] = Gs[lq*33 + i];
    }
    unsigned gh[8], gl[8];
    #pragma unroll
    for (int p = 0; p < 8; ++p) {
      float a = g[2*p], bb = g[2*p+1];
      _Float16 ha = (_Float16)a, hb = (_Float16)bb;
      gh[p] = (unsigned)__builtin_bit_cast(unsigned short, ha) |
              ((unsigned)__builtin_bit_cast(unsigned short, hb) << 16);
      gl[p] = pack_h2(a - (float)ha, bb - (float)hb);
    }
    G0h = frag4h(gh[0],gh[1],gh[2],gh[3]);
    G1h = frag4h(gh[4],gh[5],gh[6],gh[7]);
    G0l = frag4h(gl[0],gl[1],gl[2],gl[3]);
    G1l = frag4h(gl[4],gl[5],gl[6],gl[7]);
  }
  __syncthreads();   // LDS reused by merge

  f32x16 oacc;
  #pragma unroll
  for (int r = 0; r < 16; ++r) oacc[r] = 0.f;
  float m = -INFINITY, l = 0.f;

  const char* Ab = ws + OFF_A + (size_t)(b*16 + grp*4)*8192;
  const char* Tb = ws + OFF_T + (size_t)(b*16 + grp*4)*4096;
  const int lo16 = lane*16;

  #pragma unroll 2
  for (int j = 0; j < 4; ++j) {
    const char* A = Ab + j*8192;
    const char* T = Tb + j*4096;
    f16x8 ah0 = ldh(A + 0*1024 + lo16);
    f16x8 ah1 = ldh(A + 1*1024 + lo16);
    f16x8 ah2 = ldh(A + 2*1024 + lo16);
    f16x8 ah3 = ldh(A + 3*1024 + lo16);
    f16x8 al0 = ldh(A + 4096 + 0*1024 + lo16);
    f16x8 al1 = ldh(A + 4096 + 1*1024 + lo16);
    f16x8 al2 = ldh(A + 4096 + 2*1024 + lo16);
    f16x8 al3 = ldh(A + 4096 + 3*1024 + lo16);
    f16x8 at0 = ldh(T + 0*1024 + lo16);
    f16x8 at1 = ldh(T + 1*1024 + lo16);
    f16x8 at2 = ldh(T + 2*1024 + lo16);
    f16x8 at3 = ldh(T + 3*1024 + lo16);

    // ---- GEMM1: S^T[64k x 32q], 3-term fp16 split (exp2 domain) ----
    f32x16 sa0, sa1;
    #pragma unroll
    for (int r = 0; r < 16; ++r) { sa0[r] = 0.f; sa1[r] = 0.f; }
    sa0 = MFMA32H(ah0, G0h, sa0); sa0 = MFMA32H(ah0, G0l, sa0); sa0 = MFMA32H(al0, G0h, sa0);
    sa0 = MFMA32H(ah1, G1h, sa0); sa0 = MFMA32H(ah1, G1l, sa0); sa0 = MFMA32H(al1, G1h, sa0);
    sa1 = MFMA32H(ah2, G0h, sa1); sa1 = MFMA32H(ah2, G0l, sa1); sa1 = MFMA32H(al2, G0h, sa1);
    sa1 = MFMA32H(ah3, G1h, sa1); sa1 = MFMA32H(ah3, G1l, sa1); sa1 = MFMA32H(al3, G1h, sa1);

    // ---- online softmax: tree max, defer-max (8*log2e), tree sum ----
    float t0 = fmaxf(fmaxf(sa0[0], sa0[1]),  fmaxf(sa0[2],  sa0[3]));
    float t1 = fmaxf(fmaxf(sa0[4], sa0[5]),  fmaxf(sa0[6],  sa0[7]));
    float t2 = fmaxf(fmaxf(sa0[8], sa0[9]),  fmaxf(sa0[10], sa0[11]));
    float t3 = fmaxf(fmaxf(sa0[12],sa0[13]), fmaxf(sa0[14], sa0[15]));
    float t4 = fmaxf(fmaxf(sa1[0], sa1[1]),  fmaxf(sa1[2],  sa1[3]));
    float t5 = fmaxf(fmaxf(sa1[4], sa1[5]),  fmaxf(sa1[6],  sa1[7]));
    float t6 = fmaxf(fmaxf(sa1[8], sa1[9]),  fmaxf(sa1[10], sa1[11]));
    float t7 = fmaxf(fmaxf(sa1[12],sa1[13]), fmaxf(sa1[14], sa1[15]));
    float tm = fmaxf(fmaxf(fmaxf(t0,t1), fmaxf(t2,t3)),
                     fmaxf(fmaxf(t4,t5), fmaxf(t6,t7)));
    tm = cross_max(tm);
    if (!__all(tm - m <= 11.5415603f)) {    // = 8 * log2(e)
      float mn = fmaxf(m, tm);
      float alpha = ex2(m - mn);
      m = mn;
      l *= alpha;
      #pragma unroll
      for (int r = 0; r < 16; ++r) oacc[r] *= alpha;
    }
    #pragma unroll
    for (int r = 0; r < 16; ++r) { sa0[r] = ex2(sa0[r] - m); sa1[r] = ex2(sa1[r] - m); }
    float s0 = (sa0[0] + sa0[1])  + (sa0[2]  + sa0[3]);
    float s1 = (sa0[4] + sa0[5])  + (sa0[6]  + sa0[7]);
    float s2 = (sa0[8] + sa0[9])  + (sa0[10] + sa0[11]);
    float s3 = (sa0[12]+ sa0[13]) + (sa0[14] + sa0[15]);
    float s4 = (sa1[0] + sa1[1])  + (sa1[2]  + sa1[3]);
    float s5 = (sa1[4] + sa1[5])  + (sa1[6]  + sa1[7]);
    float s6 = (sa1[8] + sa1[9])  + (sa1[10] + sa1[11]);
    float s7 = (sa1[12]+ sa1[13]) + (sa1[14] + sa1[15]);
    float ps = ((s0+s1) + (s2+s3)) + ((s4+s5) + (s6+s7));
    ps = cross_add(ps);
    l += ps;

    // ---- GEMM2: O^T += xkT * P (dst=low-pair) ----
    {
      unsigned u0 = pkh(sa0[0], sa0[1]),  u1 = pkh(sa0[2], sa0[3]);
      unsigned v0 = pkh(sa0[4], sa0[5]),  v1 = pkh(sa0[6], sa0[7]);
      plswap(u0, v0); plswap(u1, v1);
      oacc = MFMA32H(at0, frag4h(u0, u1, v0, v1), oacc);

      unsigned u2 = pkh(sa0[8], sa0[9]),   u3 = pkh(sa0[10], sa0[11]);
      unsigned v2 = pkh(sa0[12], sa0[13]), v3 = pkh(sa0[14], sa0[15]);
      plswap(u2, v2); plswap(u3, v3);
      oacc = MFMA32H(at1, frag4h(u2, u3, v2, v3), oacc);

      unsigned u4 = pkh(sa1[0], sa1[1]),  u5 = pkh(sa1[2], sa1[3]);
      unsigned v4 = pkh(sa1[4], sa1[5]),  v5 = pkh(sa1[6], sa1[7]);
      plswap(u4, v4); plswap(u5, v5);
      oacc = MFMA32H(at2, frag4h(u4, u5, v4, v5), oacc);

      unsigned u6 = pkh(sa1[8], sa1[9]),   u7 = pkh(sa1[10], sa1[11]);
      unsigned v6 = pkh(sa1[12], sa1[13]), v7 = pkh(sa1[14], sa1[15]);
      plswap(u6, v6); plswap(u7, v7);
      oacc = MFMA32H(at3, frag4h(u6, u7, v6, v7), oacc);
    }
  }

  // ---- 4-way flash-merge across waves (symmetric, exp2 domain) ----
  {
    float* ms = (float*)(smem + ((wid<<6) | lane) * 80);
    *(float4*)(ms + 0)  = (float4){oacc[0],  oacc[1],  oacc[2],  oacc[3]};
    *(float4*)(ms + 4)  = (float4){oacc[4],  oacc[5],  oacc[6],  oacc[7]};
    *(float4*)(ms + 8)  = (float4){oacc[8],  oacc[9],  oacc[10], oacc[11]};
    *(float4*)(ms + 12) = (float4){oacc[12], oacc[13], oacc[14], oacc[15]};
    ms[16] = m; ms[17] = l;
    __syncthreads();
    #pragma unroll
    for (int og = 0; og < 4; ++og) {
      if (og == wid) continue;
      const float* pp = (const float*)(smem + ((og<<6) | lane) * 80);
      float4 p0 = *(const float4*)(pp + 0);
      float4 p1 = *(const float4*)(pp + 4);
      float4 p2 = *(const float4*)(pp + 8);
      float4 p3 = *(const float4*)(pp + 12);
      float pm = pp[16], pl = pp[17];
      float mf = fmaxf(m, pm);
      float as = ex2(m - mf), ap = ex2(pm - mf);
      l = l * as + pl * ap;
      float po[16] = {p0.x,p0.y,p0.z,p0.w, p1.x,p1.y,p1.z,p1.w,
                      p2.x,p2.y,p2.z,p2.w, p3.x,p3.y,p3.z,p3.w};
      #pragma unroll
      for (int r = 0; r < 16; ++r) oacc[r] = oacc[r] * as + po[r] * ap;
      m = mf;
    }
    __syncthreads();   // before zb reuse of this region
  }

  // ---- epilogue: Z^T = WvT * O_norm; wave handles mt = wid*2 + {0,1} ----
  float inv = 1.0f / (16.0f * l);
  #pragma unroll
  for (int r = 0; r < 16; ++r) oacc[r] *= inv;
  f16x8 of0, of1;
  {
    unsigned u0 = pkh(oacc[0], oacc[1]),  u1 = pkh(oacc[2], oacc[3]);
    unsigned v0 = pkh(oacc[4], oacc[5]),  v1 = pkh(oacc[6], oacc[7]);
    plswap(u0, v0); plswap(u1, v1);
    of0 = frag4h(u0, u1, v0, v1);
    unsigned u2 = pkh(oacc[8], oacc[9]),   u3 = pkh(oacc[10], oacc[11]);
    unsigned v2 = pkh(oacc[12], oacc[13]), v3 = pkh(oacc[14], oacc[15]);
    plswap(u2, v2); plswap(u3, v3);
    of1 = frag4h(u2, u3, v2, v3);
  }
  const char* WvTb = ws + OFF_WVT;
  float* zb = (float*)(smem + wid * 4224);
  const size_t orow = ((size_t)b * SEQ + q0);
  #pragma unroll 1
  for (int mi = 0; mi < 2; ++mi) {
    const int mt = wid*2 + mi;
    const char* wp = WvTb + (mt*32 + lq)*64 + 16*w;
    f16x8 a0 = ldh(wp);
    f16x8 a1 = ldh(wp + 32);
    f32x16 z;
    #pragma unroll
    for (int r = 0; r < 16; ++r) z[r] = 0.f;
    z = MFMA32H(a0, of0, z);
    z = MFMA32H(a1, of1, z);
    #pragma unroll
    for (int r = 0; r < 16; ++r) {
      int hl = (r&3) + 8*(r>>2) + 4*w;
      zb[hl*33 + lq] = z[r];
    }
    asm volatile("s_waitcnt lgkmcnt(0)" ::: "memory");
    float bvv = bv[mt*32 + lq] * 0.0625f;
    #pragma unroll
    for (int jj = 0; jj < 16; ++jj) {
      int q = w*16 + jj;
      out[(orow + q)*HID + mt*32 + lq] = zb[lq*33 + q] + bvv;
    }
    asm volatile("s_waitcnt lgkmcnt(0)" ::: "memory");
  }
}

// ====================== FALLBACK (round-6, proven) ======================

__global__ void precompute_kernel(const float* __restrict__ Wq, const float* __restrict__ Wk,
                                  const float* __restrict__ bq, const float* __restrict__ Wv,
                                  float* __restrict__ ws) {
  const int gid = blockIdx.x * 256 + threadIdx.x;
  if (gid < 1024) {
    int i = gid >> 5, j = gid & 31;
    const float* a  = Wq + j * HID;
    const float* b2 = Wk + i * HID;
    float a0=0.f,a1=0.f,a2=0.f,a3=0.f;
    for (int h = 0; h < HID; h += 8) {
      float4 x1 = *(const float4*)(a + h),  y1 = *(const float4*)(b2 + h);
      float4 x2 = *(const float4*)(a + h+4), y2 = *(const float4*)(b2 + h+4);
      a0 = fmaf(x1.x,y1.x,a0); a1 = fmaf(x1.y,y1.y,a1);
      a2 = fmaf(x1.z,y1.z,a2); a3 = fmaf(x1.w,y1.w,a3);
      a0 = fmaf(x2.x,y2.x,a0); a1 = fmaf(x2.y,y2.y,a1);
      a2 = fmaf(x2.z,y2.z,a2); a3 = fmaf(x2.w,y2.w,a3);
    }
    ws[gid] = (a0+a1)+(a2+a3);
  } else if (gid < 1056) {
    int i2 = gid - 1024;
    const float* b2 = Wk + i2 * HID;
    float acc = 0.f;
    for (int h = 0; h < HID; ++h) acc = fmaf(b2[h], bq[h], acc);
    ws[1024 + i2] = acc;
  } else if (gid < 1056 + HID*16) {
    int e = gid - 1056;
    int h = e >> 4, d = e & 15;
    ((unsigned*)((char*)ws + 4224))[e] = pk_bf16(Wv[(2*d)*HID + h], Wv[(2*d+1)*HID + h]);
  }
}

__global__ __launch_bounds__(512, 4) void attn_kernel(
    const float* __restrict__ x, const float* __restrict__ ws,
    const float* __restrict__ bv, float* __restrict__ out) {
  __shared__ __align__(16) char smem[SMEM_SZ];
  const int b    = blockIdx.y;
  const int q0   = blockIdx.x * QT;
  const int t    = threadIdx.x;
  const int grp  = t >> 8;
  const int ts   = t & 255;
  const int wid  = t >> 6;
  const int wq   = wid & 3;
  const int lane = t & 63;
  const int w    = lane >> 5;
  const int lq   = lane & 31;
  const float* xb = x + (size_t)b * SEQ * DIN;

  float* ATs = (float*)(smem + ATS_OFF);
  for (int e = t; e < 1056; e += 512) ATs[e] = ws[e];

  {
    const int sb = SETB(grp, 0);
    const int r = ts >> 2, s4 = ts & 3;
    const float* src = xb + (size_t)(grp * KT + r) * DIN + s4 * 8;
    float4 va = *(const float4*)src;
    float4 vb = *(const float4*)(src + 4);
    unsigned h0 = bf16_hi_bits(va.x) | (bf16_hi_bits(va.y) << 16);
    unsigned h1 = bf16_hi_bits(va.z) | (bf16_hi_bits(va.w) << 16);
    unsigned h2 = bf16_hi_bits(vb.x) | (bf16_hi_bits(vb.y) << 16);
    unsigned h3 = bf16_hi_bits(vb.z) | (bf16_hi_bits(vb.w) << 16);
    unsigned l0 = bf16_hi_bits(va.x - __uint_as_float(h0<<16)) | (bf16_hi_bits(va.y - __uint_as_float(h0 & 0xffff0000u)) << 16);
    unsigned l1 = bf16_hi_bits(va.z - __uint_as_float(h1<<16)) | (bf16_hi_bits(va.w - __uint_as_float(h1 & 0xffff0000u)) << 16);
    unsigned l2 = bf16_hi_bits(vb.x - __uint_as_float(h2<<16)) | (bf16_hi_bits(vb.y - __uint_as_float(h2 & 0xffff0000u)) << 16);
    unsigned l3 = bf16_hi_bits(vb.z - __uint_as_float(h3<<16)) | (bf16_hi_bits(vb.w - __uint_as_float(h3 & 0xffff0000u)) << 16);
    int off = r*64 + ((s4 ^ (r & 3)) << 4);
    *(u32x4v*)(smem + sb + off)        = (u32x4v){h0,h1,h2,h3};
    *(u32x4v*)(smem + sb + 4096 + off) = (u32x4v){l0,l1,l2,l3};
    const int ci = ts & 31, cr = (ts >> 5) * 8;
    const float* cs = xb + (size_t)(grp * KT + cr) * DIN + ci;
    float c0=cs[0], c1=cs[DIN], c2=cs[2*DIN], c3=cs[3*DIN];
    float c4=cs[4*DIN], c5=cs[5*DIN], c6=cs[6*DIN], c7=cs[7*DIN];
    unsigned t0 = pk_bf16(c0,c1), t1 = pk_bf16(c2,c3), t2 = pk_bf16(c4,c5), t3 = pk_bf16(c6,c7);
    int toff = sb + 8192 + ci*128 + (((ts>>5) ^ (ci & 7)) << 4);
    *(u32x4v*)(smem + toff) = (u32x4v){t0,t1,t2,t3};
  }
  __syncthreads();

  float g[16];
  {
    float xq[32];
    const float* xrow = xb + (size_t)(q0 + wq*32 + lq) * DIN;
    #pragma unroll
    for (int c = 0; c < 8; ++c) {
      float4 v = *(const float4*)(xrow + c*4);
      xq[c*4+0]=v.x; xq[c*4+1]=v.y; xq[c*4+2]=v.z; xq[c*4+3]=v.w;
    }
    #pragma unroll
    for (int ii = 0; ii < 16; ++ii) {
      const int i = 8*w + 16*(ii>>3) + (ii&7);
      const float* ar = ATs + i*32;
      float acc = ATs[1024 + i];
      #pragma unroll
      for (int j = 0; j < 8; ++j) {
        float4 av = *(const float4*)(ar + j*4);
        acc = fmaf(xq[j*4+0], av.x, acc);
        acc = fmaf(xq[j*4+1], av.y, acc);
        acc = fmaf(xq[j*4+2], av.z, acc);
        acc = fmaf(xq[j*4+3], av.w, acc);
      }
      g[ii] = acc;
    }
  }
  s16x8 G0h, G0l, G1h, G1l;
  {
    unsigned gh[2][4], gl[2][4];
    #pragma unroll
    for (int Ks = 0; Ks < 2; ++Ks)
      #pragma unroll
      for (int d = 0; d < 4; ++d) {
        float ga = g[Ks*8 + 2*d], gb = g[Ks*8 + 2*d + 1];
        unsigned hp = bf16_hi_bits(ga) | (bf16_hi_bits(gb) << 16);
        unsigned lp = bf16_hi_bits(ga - __uint_as_float(hp<<16)) |
                      (bf16_hi_bits(gb - __uint_as_float(hp & 0xffff0000u)) << 16);
        gh[Ks][d] = hp; gl[Ks][d] = lp;
      }
    G0h = frag4(gh[0][0],gh[0][1],gh[0][2],gh[0][3]);
    G0l = frag4(gl[0][0],gl[0][1],gl[0][2],gl[0][3]);
    G1h = frag4(gh[1][0],gh[1][1],gh[1][2],gh[1][3]);
    G1l = frag4(gl[1][0],gl[1][1],gl[1][2],gl[1][3]);
  }

  f32x16 oacc;
  #pragma unroll
  for (int r = 0; r < 16; ++r) oacc[r] = 0.f;
  float m = -INFINITY, l = 0.f;

  for (int j = 0; j < NKT/2; ++j) {
    const bool hn = (j + 1 < NKT/2);
    float4 va, vb;
    float c0=0,c1=0,c2=0,c3=0,c4=0,c5=0,c6=0,c7=0;
    if (hn) {
      const int ktn = 2*(j+1) + grp;
      const int r = ts >> 2, s4 = ts & 3;
      const float* src = xb + (size_t)(ktn*KT + r) * DIN + s4*8;
      va = *(const float4*)src;
      vb = *(const float4*)(src + 4);
      const int ci = ts & 31, cr = (ts >> 5) * 8;
      const float* cs = xb + (size_t)(ktn*KT + cr) * DIN + ci;
      c0=cs[0]; c1=cs[DIN]; c2=cs[2*DIN]; c3=cs[3*DIN];
      c4=cs[4*DIN]; c5=cs[5*DIN]; c6=cs[6*DIN]; c7=cs[7*DIN];
    }

    const int sb = SETB(grp, j & 1);
    const char* bh = smem + sb;
    const char* bl = smem + sb + 4096;
    const int co0 = ((w    ) ^ (lq & 3)) << 4;
    const int co1 = ((w + 2) ^ (lq & 3)) << 4;
    s16x8 ah00 = *(const s16x8*)(bh + lq*64 + co0);
    s16x8 ah01 = *(const s16x8*)(bh + lq*64 + co1);
    s16x8 al00 = *(const s16x8*)(bl + lq*64 + co0);
    s16x8 al01 = *(const s16x8*)(bl + lq*64 + co1);
    s16x8 ah10 = *(const s16x8*)(bh + (32+lq)*64 + co0);
    s16x8 ah11 = *(const s16x8*)(bh + (32+lq)*64 + co1);
    s16x8 al10 = *(const s16x8*)(bl + (32+lq)*64 + co0);
    s16x8 al11 = *(const s16x8*)(bl + (32+lq)*64 + co1);
    f32x16 sa0, sa1;
    #pragma unroll
    for (int r = 0; r < 16; ++r) { sa0[r] = 0.f; sa1[r] = 0.f; }
    sa0 = MFMA32(ah00, G0h, sa0); sa0 = MFMA32(ah00, G0l, sa0); sa0 = MFMA32(al00, G0h, sa0);
    sa0 = MFMA32(ah01, G1h, sa0); sa0 = MFMA32(ah01, G1l, sa0); sa0 = MFMA32(al01, G1h, sa0);
    sa1 = MFMA32(ah10, G0h, sa1); sa1 = MFMA32(ah10, G0l, sa1); sa1 = MFMA32(al10, G0h, sa1);
    sa1 = MFMA32(ah11, G1h, sa1); sa1 = MFMA32(ah11, G1l, sa1); sa1 = MFMA32(al11, G1h, sa1);

    float tm = sa0[0];
    #pragma unroll
    for (int r = 1; r < 16; ++r) tm = fmaxf(tm, sa0[r]);
    #pragma unroll
    for (int r = 0; r < 16; ++r) tm = fmaxf(tm, sa1[r]);
    tm = cross_max(tm);
    float mn = fmaxf(m, tm);
    float alpha = __expf(m - mn);
    m = mn;
    float ps = 0.f;
    #pragma unroll
    for (int r = 0; r < 16; ++r) { float p = __expf(sa0[r] - mn); sa0[r] = p; ps += p; }
    #pragma unroll
    for (int r = 0; r < 16; ++r) { float p = __expf(sa1[r] - mn); sa1[r] = p; ps += p; }
    ps = cross_add(ps);
    l = l * alpha + ps;
    #pragma unroll
    for (int r = 0; r < 16; ++r) oacc[r] *= alpha;

    const char* bt = smem + sb + 8192;
    {
      unsigned u0 = pk_bf16(sa0[0], sa0[1]),  u1 = pk_bf16(sa0[2], sa0[3]);
      unsigned v0 = pk_bf16(sa0[4], sa0[5]),  v1 = pk_bf16(sa0[6], sa0[7]);
      plswap(u0, v0); plswap(u1, v1);
      s16x8 at0 = *(const s16x8*)(bt + lq*128 + (((0 + w) ^ (lq & 7)) << 4));
      oacc = MFMA32(at0, frag4(u0, u1, v0, v1), oacc);

      unsigned u2 = pk_bf16(sa0[8], sa0[9]),   u3 = pk_bf16(sa0[10], sa0[11]);
      unsigned v2 = pk_bf16(sa0[12], sa0[13]), v3 = pk_bf16(sa0[14], sa0[15]);
      plswap(u2, v2); plswap(u3, v3);
      s16x8 at1 = *(const s16x8*)(bt + lq*128 + (((2 + w) ^ (lq & 7)) << 4));
      oacc = MFMA32(at1, frag4(u2, u3, v2, v3), oacc);

      unsigned u4 = pk_bf16(sa1[0], sa1[1]),  u5 = pk_bf16(sa1[2], sa1[3]);
      unsigned v4 = pk_bf16(sa1[4], sa1[5]),  v5 = pk_bf16(sa1[6], sa1[7]);
      plswap(u4, v4); plswap(u5, v5);
      s16x8 at2 = *(const s16x8*)(bt + lq*128 + (((4 + w) ^ (lq & 7)) << 4));
      oacc = MFMA32(at2, frag4(u4, u5, v4, v5), oacc);

      unsigned u6 = pk_bf16(sa1[8], sa1[9]),   u7 = pk_bf16(sa1[10], sa1[11]);
      unsigned v6 = pk_bf16(sa1[12], sa1[13]), v7 = pk_bf16(sa1[14], sa1[15]);
      plswap(u6, v6); plswap(u7, v7);
      s16x8 at3 = *(const s16x8*)(bt + lq*128 + (((6 + w) ^ (lq & 7)) << 4));
      oacc = MFMA32(at3, frag4(u6, u7, v6, v7), oacc);
    }

    if (hn) {
      const int nsb = SETB(grp, (j+1) & 1);
      const int r = ts >> 2, s4 = ts & 3;
      unsigned h0 = bf16_hi_bits(va.x) | (bf16_hi_bits(va.y) << 16);
      unsigned h1 = bf16_hi_bits(va.z) | (bf16_hi_bits(va.w) << 16);
      unsigned h2 = bf16_hi_bits(vb.x) | (bf16_hi_bits(vb.y) << 16);
      unsigned h3 = bf16_hi_bits(vb.z) | (bf16_hi_bits(vb.w) << 16);
      unsigned l0 = bf16_hi_bits(va.x - __uint_as_float(h0<<16)) | (bf16_hi_bits(va.y - __uint_as_float(h0 & 0xffff0000u)) << 16);
      unsigned l1 = bf16_hi_bits(va.z - __uint_as_float(h1<<16)) | (bf16_hi_bits(va.w - __uint_as_float(h1 & 0xffff0000u)) << 16);
      unsigned l2 = bf16_hi_bits(vb.x - __uint_as_float(h2<<16)) | (bf16_hi_bits(vb.y - __uint_as_float(h2 & 0xffff0000u)) << 16);
      unsigned l3 = bf16_hi_bits(vb.z - __uint_as_float(h3<<16)) | (bf16_hi_bits(vb.w - __uint_as_float(h3 & 0xffff0000u)) << 16);
      int off = r*64 + ((s4 ^ (r & 3)) << 4);
      *(u32x4v*)(smem + nsb + off)        = (u32x4v){h0,h1,h2,h3};
      *(u32x4v*)(smem + nsb + 4096 + off) = (u32x4v){l0,l1,l2,l3};
      const int ci = ts & 31;
      unsigned t0 = pk_bf16(c0,c1), t1 = pk_bf16(c2,c3), t2 = pk_bf16(c4,c5), t3 = pk_bf16(c6,c7);
      int toff = nsb + 8192 + ci*128 + (((ts>>5) ^ (ci & 7)) << 4);
      *(u32x4v*)(smem + toff) = (u32x4v){t0,t1,t2,t3};
    }
    __syncthreads();
  }

  {
    float* ms = (float*)(smem + grp*20480 + (((wq<<6) | lane) * 80));
    *(float4*)(ms + 0)  = (float4){oacc[0],  oacc[1],  oacc[2],  oacc[3]};
    *(float4*)(ms + 4)  = (float4){oacc[4],  oacc[5],  oacc[6],  oacc[7]};
    *(float4*)(ms + 8)  = (float4){oacc[8],  oacc[9],  oacc[10], oacc[11]};
    *(float4*)(ms + 12) = (float4){oacc[12], oacc[13], oacc[14], oacc[15]};
    ms[16] = m; ms[17] = l;
    __syncthreads();
    const float* pp = (const float*)(smem + (1-grp)*20480 + (((wq<<6) | lane) * 80));
    float4 p0 = *(const float4*)(pp + 0);
    float4 p1 = *(const float4*)(pp + 4);
    float4 p2 = *(const float4*)(pp + 8);
    float4 p3 = *(const float4*)(pp + 12);
    float pm = pp[16], pl = pp[17];
    float mf = fmaxf(m, pm);
    float as = __expf(m - mf), ap = __expf(pm - mf);
    l = l * as + pl * ap;
    float po[16] = {p0.x,p0.y,p0.z,p0.w, p1.x,p1.y,p1.z,p1.w,
                    p2.x,p2.y,p2.z,p2.w, p3.x,p3.y,p3.z,p3.w};
    #pragma unroll
    for (int r = 0; r < 16; ++r) oacc[r] = oacc[r] * as + po[r] * ap;
    __syncthreads();
  }

  float inv = 1.0f / (16.0f * l);
  #pragma unroll
  for (int r = 0; r < 16; ++r) oacc[r] *= inv;
  s16x8 of0, of1;
  {
    unsigned u0 = pk_bf16(oacc[0], oacc[1]),  u1 = pk_bf16(oacc[2], oacc[3]);
    unsigned v0 = pk_bf16(oacc[4], oacc[5]),  v1 = pk_bf16(oacc[6], oacc[7]);
    plswap(u0, v0); plswap(u1, v1);
    of0 = frag4(u0, u1, v0, v1);
    unsigned u2 = pk_bf16(oacc[8], oacc[9]),   u3 = pk_bf16(oacc[10], oacc[11]);
    unsigned v2 = pk_bf16(oacc[12], oacc[13]), v3 = pk_bf16(oacc[14], oacc[15]);
    plswap(u2, v2); plswap(u3, v3);
    of1 = frag4(u2, u3, v2, v3);
  }
  const char* WvTb = (const char*)ws + 4224;
  float* zb = (float*)(smem + wid * 4224);
  const size_t orow = ((size_t)b * SEQ + q0 + wq*32);
  #pragma unroll 1
  for (int mi = 0; mi < 4; ++mi) {
    const int mt = grp*4 + mi;
    const char* wp = WvTb + (mt*32 + lq)*64 + 16*w;
    s16x8 a0 = *(const s16x8*)wp;
    s16x8 a1 = *(const s16x8*)(wp + 32);
    f32x16 z;
    #pragma unroll
    for (int r = 0; r < 16; ++r) z[r] = 0.f;
    z = MFMA32(a0, of0, z);
    z = MFMA32(a1, of1, z);
    #pragma unroll
    for (int r = 0; r < 16; ++r) {
      int hl = (r&3) + 8*(r>>2) + 4*w;
      zb[hl*33 + lq] = z[r];
    }
    asm volatile("s_waitcnt lgkmcnt(0)" ::: "memory");
    float bvv = bv[mt*32 + lq] * 0.0625f;
    #pragma unroll
    for (int jj = 0; jj < 16; ++jj) {
      int q = w*16 + jj;
      out[(orow + q)*HID + mt*32 + lq] = zb[lq*33 + q] + bvv;
    }
    asm volatile("s_waitcnt lgkmcnt(0)" ::: "memory");
  }
}

extern "C" void kernel_launch(void* const* d_in, const int* in_sizes, int n_in,
                              void* d_out, int out_size, void* d_ws, size_t ws_size,
                              hipStream_t stream) {
  (void)in_sizes; (void)n_in; (void)out_size;
  const float* x  = (const float*)d_in[0];
  const float* Wq = (const float*)d_in[1];
  const float* bq = (const float*)d_in[2];
  const float* Wk = (const float*)d_in[3];
  const float* Wv = (const float*)d_in[5];
  const float* bv = (const float*)d_in[6];
  float* out = (float*)d_out;
  float* ws  = (float*)d_ws;

  if (ws_size >= WS_NEED) {
    pack2_kernel<<<1048, 256, 0, stream>>>(x, Wq, Wk, bq, Wv, (char*)ws);
    attn_fast<<<2048, 256, 0, stream>>>(x, (const char*)ws, bv, out);
  } else {
    precompute_kernel<<<24, 256, 0, stream>>>(Wq, Wk, bq, Wv, ws);
    attn_kernel<<<dim3(SEQ/QT, NB), 512, 0, stream>>>(x, ws, bv, out);
  }
}